// Round 1
// baseline (10540.476 us; speedup 1.0000x reference)
//
#include <hip/hip_runtime.h>
#include <math.h>

constexpr int B = 4, T = 2048, C = 1024, H = 16, D = 64;
constexpr int M = B * T;            // 8192 GEMM rows
constexpr size_t BTC = (size_t)B * T * C;

// ---------------------------------------------------------------------------
// GEMM: out[m,n] = sum_k A[m,k] * Wt[n,k] + bias[n]   (A: MxK, Wt: NxK)
// 64x64 tile, BK=16, 256 threads, 4x4 micro-tile per thread. fp32.
// ---------------------------------------------------------------------------
#define TILE 64
#define BK 16
__global__ __launch_bounds__(256) void gemm_bt(
    const float* __restrict__ A, const float* __restrict__ Wt,
    const float* __restrict__ bias, float* __restrict__ out,
    int Mm, int N, int K) {
  __shared__ float As[BK][TILE + 1];
  __shared__ float Bs[BK][TILE + 1];
  int tid = threadIdx.x;
  int tx = tid % 16;   // output col group (4 cols)
  int ty = tid / 16;   // output row group (4 rows)
  int row0 = blockIdx.y * TILE;
  int col0 = blockIdx.x * TILE;
  float acc[4][4] = {};
  for (int k0 = 0; k0 < K; k0 += BK) {
#pragma unroll
    for (int i = 0; i < 4; i++) {
      int idx = tid + i * 256;      // 0..1023
      int m = idx / BK;             // 0..63
      int kk = idx % BK;            // 0..15
      As[kk][m] = A[(size_t)(row0 + m) * K + k0 + kk];
      Bs[kk][m] = Wt[(size_t)(col0 + m) * K + k0 + kk];
    }
    __syncthreads();
#pragma unroll
    for (int kk = 0; kk < BK; kk++) {
      float a[4], b[4];
#pragma unroll
      for (int i = 0; i < 4; i++) a[i] = As[kk][ty * 4 + i];
#pragma unroll
      for (int j = 0; j < 4; j++) b[j] = Bs[kk][tx * 4 + j];
#pragma unroll
      for (int i = 0; i < 4; i++)
#pragma unroll
        for (int j = 0; j < 4; j++) acc[i][j] += a[i] * b[j];
    }
    __syncthreads();
  }
#pragma unroll
  for (int i = 0; i < 4; i++)
#pragma unroll
    for (int j = 0; j < 4; j++) {
      int m = row0 + ty * 4 + i;
      int n = col0 + tx * 4 + j;
      out[(size_t)m * N + n] = acc[i][j] + bias[n];
    }
}

// ---------------------------------------------------------------------------
// RoPE + transpose (B,T,H,D) -> (B,H,T,D). One thread per (b,h,t,i<32) pair.
// ---------------------------------------------------------------------------
__global__ __launch_bounds__(256) void rope_transpose(
    const float* __restrict__ in, float* __restrict__ outp) {
  int idx = blockIdx.x * blockDim.x + threadIdx.x;  // B*H*T*32 total
  int i = idx & 31;
  int t = (idx >> 5) & (T - 1);
  int h = (idx >> 16) & (H - 1);   // 5 + 11 = 16 bits below
  int b = idx >> 20;
  const float* src = in + ((size_t)b * T + t) * C + h * D;
  float xr = src[i];
  float xi = src[i + 32];
  float alpha = powf(10000.f, -(float)i / 32.f);
  float ang = (float)t * alpha;
  float c = cosf(ang), s = sinf(ang);
  float* dst = outp + (((size_t)b * H + h) * T + t) * D;
  dst[i]      = xr * c - xi * s;
  dst[i + 32] = xr * s + xi * c;
}

// ---------------------------------------------------------------------------
// Plain transpose (B,T,H,D) -> (B,H,T,D) for V.
// ---------------------------------------------------------------------------
__global__ __launch_bounds__(256) void transpose_v(
    const float* __restrict__ in, float* __restrict__ outp) {
  int idx = blockIdx.x * blockDim.x + threadIdx.x;  // B*H*T*D total
  int d = idx & (D - 1);
  int t = (idx >> 6) & (T - 1);
  int h = (idx >> 17) & (H - 1);
  int b = idx >> 21;
  outp[idx] = in[((size_t)b * T + t) * C + h * D + d];
}

// ---------------------------------------------------------------------------
// Causal flash attention, one wave per query row. q,k,v: (B,H,T,D) fp32.
// Output written to (B,T,C) layout.
// ---------------------------------------------------------------------------
__global__ __launch_bounds__(256) void attn(
    const float* __restrict__ q, const float* __restrict__ k,
    const float* __restrict__ v, float* __restrict__ y) {
  int wave = threadIdx.x >> 6;
  int lane = threadIdx.x & 63;
  int row = blockIdx.x * 4 + wave;   // global row over B*H*T
  int t = row & (T - 1);
  int bh = row >> 11;                // T = 2048 = 2^11
  const float* qrow = q + (size_t)row * D;
  const float* kbase = k + (size_t)bh * T * D;
  const float* vbase = v + (size_t)bh * T * D;
  float qd = qrow[lane] * 0.125f;    // fold scale 1/sqrt(64)
  float m = -INFINITY, l = 0.f, acc = 0.f;
  for (int s = 0; s <= t; s++) {
    float p = qd * kbase[(size_t)s * D + lane];
#pragma unroll
    for (int off = 32; off; off >>= 1) p += __shfl_xor(p, off);
    float mn = fmaxf(m, p);
    float al = __expf(m - mn);
    float w = __expf(p - mn);
    l = l * al + w;
    acc = acc * al + w * vbase[(size_t)s * D + lane];
    m = mn;
  }
  int b = bh >> 4, h = bh & (H - 1);
  y[((size_t)b * T + t) * C + h * D + lane] = acc / l;
}

// ---------------------------------------------------------------------------
extern "C" void kernel_launch(void* const* d_in, const int* in_sizes, int n_in,
                              void* d_out, int out_size, void* d_ws, size_t ws_size,
                              hipStream_t stream) {
  const float* x  = (const float*)d_in[0];
  const float* wq = (const float*)d_in[1];
  const float* bq = (const float*)d_in[2];
  const float* wk = (const float*)d_in[3];
  const float* bk = (const float*)d_in[4];
  const float* wv = (const float*)d_in[5];
  const float* bv = (const float*)d_in[6];
  const float* wp = (const float*)d_in[7];
  const float* bp = (const float*)d_in[8];
  float* out = (float*)d_out;

  float* tmp0 = (float*)d_ws;        // (B,T,C) scratch
  float* qf = tmp0 + BTC;            // (B,H,T,D)
  float* kf = qf + BTC;
  float* vf = kf + BTC;

  dim3 gemm_grid(C / TILE, M / TILE);   // (16, 128)
  int rope_blocks = (B * H * T * 32) / 256;   // 16384
  int tr_blocks   = (B * H * T * D) / 256;    // 32768
  int attn_blocks = (B * H * T) / 4;          // 32768

  // Q
  gemm_bt<<<gemm_grid, 256, 0, stream>>>(x, wq, bq, tmp0, M, C, C);
  rope_transpose<<<rope_blocks, 256, 0, stream>>>(tmp0, qf);
  // K
  gemm_bt<<<gemm_grid, 256, 0, stream>>>(x, wk, bk, tmp0, M, C, C);
  rope_transpose<<<rope_blocks, 256, 0, stream>>>(tmp0, kf);
  // V
  gemm_bt<<<gemm_grid, 256, 0, stream>>>(x, wv, bv, tmp0, M, C, C);
  transpose_v<<<tr_blocks, 256, 0, stream>>>(tmp0, vf);
  // attention -> tmp0 (B,T,C)
  attn<<<attn_blocks, 256, 0, stream>>>(qf, kf, vf, tmp0);
  // output projection
  gemm_bt<<<gemm_grid, 256, 0, stream>>>(tmp0, wp, bp, out, M, C, C);
}

// Round 2
// 1869.472 us; speedup vs baseline: 5.6382x; 5.6382x over previous
//
#include <hip/hip_runtime.h>
#include <math.h>

constexpr int B = 4, T = 2048, C = 1024, H = 16, D = 64;
constexpr int M = B * T;            // 8192 GEMM rows
constexpr size_t BTC = (size_t)B * T * C;

typedef short bf16x8 __attribute__((ext_vector_type(8)));
typedef float f32x4 __attribute__((ext_vector_type(4)));

__device__ inline ushort f2bf(float f) {
  union { float f; unsigned u; } cv; cv.f = f;
  unsigned u = cv.u;
  u += 0x7fffu + ((u >> 16) & 1u);   // round-to-nearest-even
  return (ushort)(u >> 16);
}

// ---------------------------------------------------------------------------
// GEMM: out[m,n] = sum_k A[m,k] * Wt[n,k] + bias[n]   (A: MxK, Wt: NxK) fp32
// ---------------------------------------------------------------------------
#define TILE 64
#define BK 16
__global__ __launch_bounds__(256) void gemm_bt(
    const float* __restrict__ A, const float* __restrict__ Wt,
    const float* __restrict__ bias, float* __restrict__ out,
    int Mm, int N, int K) {
  __shared__ float As[BK][TILE + 1];
  __shared__ float Bs[BK][TILE + 1];
  int tid = threadIdx.x;
  int tx = tid % 16;
  int ty = tid / 16;
  int row0 = blockIdx.y * TILE;
  int col0 = blockIdx.x * TILE;
  float acc[4][4] = {};
  for (int k0 = 0; k0 < K; k0 += BK) {
#pragma unroll
    for (int i = 0; i < 4; i++) {
      int idx = tid + i * 256;
      int m = idx / BK;
      int kk = idx % BK;
      As[kk][m] = A[(size_t)(row0 + m) * K + k0 + kk];
      Bs[kk][m] = Wt[(size_t)(col0 + m) * K + k0 + kk];
    }
    __syncthreads();
#pragma unroll
    for (int kk = 0; kk < BK; kk++) {
      float a[4], b[4];
#pragma unroll
      for (int i = 0; i < 4; i++) a[i] = As[kk][ty * 4 + i];
#pragma unroll
      for (int j = 0; j < 4; j++) b[j] = Bs[kk][tx * 4 + j];
#pragma unroll
      for (int i = 0; i < 4; i++)
#pragma unroll
        for (int j = 0; j < 4; j++) acc[i][j] += a[i] * b[j];
    }
    __syncthreads();
  }
#pragma unroll
  for (int i = 0; i < 4; i++)
#pragma unroll
    for (int j = 0; j < 4; j++) {
      int m = row0 + ty * 4 + i;
      int n = col0 + tx * 4 + j;
      out[(size_t)m * N + n] = acc[i][j] + bias[n];
    }
}

// ---------------------------------------------------------------------------
// RoPE + transpose (B,T,H,D) fp32 -> (B,H,T,D) bf16.
// ---------------------------------------------------------------------------
__global__ __launch_bounds__(256) void rope_transpose_bf16(
    const float* __restrict__ in, ushort* __restrict__ outp) {
  int idx = blockIdx.x * blockDim.x + threadIdx.x;  // B*H*T*32 total
  int i = idx & 31;
  int t = (idx >> 5) & (T - 1);
  int h = (idx >> 16) & (H - 1);
  int b = idx >> 20;
  const float* src = in + ((size_t)b * T + t) * C + h * D;
  float xr = src[i];
  float xi = src[i + 32];
  float alpha = powf(10000.f, -(float)i / 32.f);
  float ang = (float)t * alpha;
  float c = cosf(ang), s = sinf(ang);
  ushort* dst = outp + (((size_t)b * H + h) * T + t) * D;
  dst[i]      = f2bf(xr * c - xi * s);
  dst[i + 32] = f2bf(xr * s + xi * c);
}

// ---------------------------------------------------------------------------
// V transpose: (B,T,H,D) fp32 -> (B,H,D,T) bf16 (LDS-tiled, coalesced both sides)
// ---------------------------------------------------------------------------
__global__ __launch_bounds__(256) void transpose_vt(
    const float* __restrict__ in, ushort* __restrict__ outp) {
  __shared__ ushort tile[64][65];
  int bh = blockIdx.y;
  int b = bh >> 4, h = bh & 15;
  int t0 = blockIdx.x * 64;
#pragma unroll
  for (int i = 0; i < 16; i++) {
    int lin = threadIdx.x + i * 256;
    int d = lin & 63, tq = lin >> 6;
    tile[d][tq] = f2bf(in[((size_t)b * T + t0 + tq) * C + h * D + d]);
  }
  __syncthreads();
#pragma unroll
  for (int i = 0; i < 16; i++) {
    int lin = threadIdx.x + i * 256;
    int tq = lin & 63, d = lin >> 6;
    outp[((size_t)bh * D + d) * T + t0 + tq] = tile[d][tq];
  }
}

// ---------------------------------------------------------------------------
// MFMA flash attention. One wave per 16-query tile; 4 waves/block handle the
// SAME q-tile for 4 different (b,h) -> equal trip counts, __syncthreads legal.
// q,k: (B,H,T,D) bf16. vt: (B,H,D,T) bf16. y: (B,T,C) fp32.
// ---------------------------------------------------------------------------
__global__ __launch_bounds__(256) void attn_mfma(
    const ushort* __restrict__ qb, const ushort* __restrict__ kb,
    const ushort* __restrict__ vtb, float* __restrict__ y) {
  int wave = threadIdx.x >> 6, lane = threadIdx.x & 63;
  int lrow = lane & 15, quad = lane >> 4;
  int qt = blockIdx.x;
  int bh = blockIdx.y * 4 + wave;
  int b = bh >> 4, h = bh & 15;
  int q0 = qt * 16;

  __shared__ ushort Pall[4][16 * 32];
  ushort* P = Pall[wave];

  // Q A-frags: A[m=lane&15][k=quad*8+j], two d-chunks
  const ushort* qptr = qb + ((size_t)bh * T + q0 + lrow) * D + quad * 8;
  bf16x8 qa0 = *(const bf16x8*)qptr;
  bf16x8 qa1 = *(const bf16x8*)(qptr + 32);

  f32x4 o0 = {0.f, 0.f, 0.f, 0.f}, o1 = o0, o2 = o0, o3 = o0;
  float mrow[4], lsum[4];
#pragma unroll
  for (int r = 0; r < 4; r++) { mrow[r] = -1e30f; lsum[r] = 0.f; }

  int nk = (q0 + 16 + 31) / 32;   // # of 32-key tiles (causal)
  for (int kt = 0; kt < nk; kt++) {
    int s0 = kt * 32;
    // K as B-operand of Q·K^T: B[k=d][n=key] == A-frag load of row-major K
    const ushort* kp = kb + ((size_t)bh * T + s0 + lrow) * D + quad * 8;
    bf16x8 k00 = *(const bf16x8*)kp;              // keys 0-15, d 0-31
    bf16x8 k01 = *(const bf16x8*)(kp + 32);       // keys 0-15, d 32-63
    bf16x8 k10 = *(const bf16x8*)(kp + 16 * D);   // keys 16-31, d 0-31
    bf16x8 k11 = *(const bf16x8*)(kp + 16 * D + 32);
    f32x4 z = {0.f, 0.f, 0.f, 0.f};
    f32x4 s_0 = __builtin_amdgcn_mfma_f32_16x16x32_bf16(qa0, k00, z, 0, 0, 0);
    s_0 = __builtin_amdgcn_mfma_f32_16x16x32_bf16(qa1, k01, s_0, 0, 0, 0);
    f32x4 s_1 = __builtin_amdgcn_mfma_f32_16x16x32_bf16(qa0, k10, z, 0, 0, 0);
    s_1 = __builtin_amdgcn_mfma_f32_16x16x32_bf16(qa1, k11, s_1, 0, 0, 0);

    // online softmax; C/D layout: row q = quad*4+r, col = lane&15
#pragma unroll
    for (int r = 0; r < 4; r++) {
      int qrow = q0 + quad * 4 + r;
      float sv0 = s_0[r] * 0.125f;
      float sv1 = s_1[r] * 0.125f;
      if (s0 + lrow > qrow) sv0 = -1e30f;
      if (s0 + 16 + lrow > qrow) sv1 = -1e30f;
      float cm = fmaxf(sv0, sv1);
      cm = fmaxf(cm, __shfl_xor(cm, 1));
      cm = fmaxf(cm, __shfl_xor(cm, 2));
      cm = fmaxf(cm, __shfl_xor(cm, 4));
      cm = fmaxf(cm, __shfl_xor(cm, 8));
      float mn = fmaxf(mrow[r], cm);
      float alpha = __expf(mrow[r] - mn);
      mrow[r] = mn;
      float p0 = __expf(sv0 - mn), p1 = __expf(sv1 - mn);
      float rs = p0 + p1;
      rs += __shfl_xor(rs, 1);
      rs += __shfl_xor(rs, 2);
      rs += __shfl_xor(rs, 4);
      rs += __shfl_xor(rs, 8);
      lsum[r] = lsum[r] * alpha + rs;
      o0[r] *= alpha; o1[r] *= alpha; o2[r] *= alpha; o3[r] *= alpha;
      P[(quad * 4 + r) * 32 + lrow] = f2bf(p0);
      P[(quad * 4 + r) * 32 + 16 + lrow] = f2bf(p1);
    }
    __syncthreads();
    // P C-layout -> A-layout: A[m=lane&15][k=s=quad*8+j]
    bf16x8 pa = *(const bf16x8*)&P[lrow * 32 + quad * 8];
    __syncthreads();
    // PV: B[k=s][n=d] from Vt (B,H,D,T) — contiguous 16B per lane
    const ushort* vp = vtb + ((size_t)bh * D + lrow) * T + s0 + quad * 8;
    o0 = __builtin_amdgcn_mfma_f32_16x16x32_bf16(pa, *(const bf16x8*)(vp), o0, 0, 0, 0);
    o1 = __builtin_amdgcn_mfma_f32_16x16x32_bf16(pa, *(const bf16x8*)(vp + 16 * T), o1, 0, 0, 0);
    o2 = __builtin_amdgcn_mfma_f32_16x16x32_bf16(pa, *(const bf16x8*)(vp + 32 * T), o2, 0, 0, 0);
    o3 = __builtin_amdgcn_mfma_f32_16x16x32_bf16(pa, *(const bf16x8*)(vp + 48 * T), o3, 0, 0, 0);
  }

  // epilogue: normalize, store to (B,T,C) fp32
#pragma unroll
  for (int r = 0; r < 4; r++) {
    float inv = 1.f / lsum[r];
    int qrow = q0 + quad * 4 + r;
    float* dst = y + ((size_t)b * T + qrow) * C + h * D + lrow;
    dst[0]  = o0[r] * inv;
    dst[16] = o1[r] * inv;
    dst[32] = o2[r] * inv;
    dst[48] = o3[r] * inv;
  }
}

// ---------------------------------------------------------------------------
extern "C" void kernel_launch(void* const* d_in, const int* in_sizes, int n_in,
                              void* d_out, int out_size, void* d_ws, size_t ws_size,
                              hipStream_t stream) {
  const float* x  = (const float*)d_in[0];
  const float* wq = (const float*)d_in[1];
  const float* bq = (const float*)d_in[2];
  const float* wk = (const float*)d_in[3];
  const float* bk = (const float*)d_in[4];
  const float* wv = (const float*)d_in[5];
  const float* bv = (const float*)d_in[6];
  const float* wp = (const float*)d_in[7];
  const float* bp = (const float*)d_in[8];
  float* out = (float*)d_out;

  float* tmp0 = (float*)d_ws;            // (B,T,C) fp32 scratch (32 MB)
  ushort* qb  = (ushort*)(tmp0 + BTC);   // (B,H,T,D) bf16
  ushort* kb  = qb + BTC;
  ushort* vtb = kb + BTC;                // (B,H,D,T) bf16

  dim3 gemm_grid(C / TILE, M / TILE);          // (16, 128)
  int rope_blocks = (B * H * T * 32) / 256;    // 16384
  dim3 vt_grid(T / 64, B * H);                 // (32, 64)
  dim3 attn_grid(T / 16, (B * H) / 4);         // (128, 16)

  gemm_bt<<<gemm_grid, 256, 0, stream>>>(x, wq, bq, tmp0, M, C, C);
  rope_transpose_bf16<<<rope_blocks, 256, 0, stream>>>(tmp0, qb);
  gemm_bt<<<gemm_grid, 256, 0, stream>>>(x, wk, bk, tmp0, M, C, C);
  rope_transpose_bf16<<<rope_blocks, 256, 0, stream>>>(tmp0, kb);
  gemm_bt<<<gemm_grid, 256, 0, stream>>>(x, wv, bv, tmp0, M, C, C);
  transpose_vt<<<vt_grid, 256, 0, stream>>>(tmp0, vtb);
  attn_mfma<<<attn_grid, 256, 0, stream>>>(qb, kb, vtb, tmp0);
  gemm_bt<<<gemm_grid, 256, 0, stream>>>(tmp0, wp, bp, out, M, C, C);
}

// Round 3
// 653.017 us; speedup vs baseline: 16.1412x; 2.8628x over previous
//
#include <hip/hip_runtime.h>
#include <math.h>

constexpr int B = 4, T = 2048, C = 1024, H = 16, D = 64;
constexpr int M = B * T;            // 8192 GEMM rows
constexpr size_t BTC = (size_t)B * T * C;

typedef short bf16x8 __attribute__((ext_vector_type(8)));
typedef float f32x4 __attribute__((ext_vector_type(4)));

__device__ inline ushort f2bf(float f) {
  union { float f; unsigned u; } cv; cv.f = f;
  unsigned u = cv.u;
  u += 0x7fffu + ((u >> 16) & 1u);   // round-to-nearest-even
  return (ushort)(u >> 16);
}

__device__ inline void async_load16(const void* g, void* l) {
  __builtin_amdgcn_global_load_lds(
      (const __attribute__((address_space(1))) void*)g,
      (__attribute__((address_space(3))) void*)l, 16, 0, 0);
}

// ---------------------------------------------------------------------------
// fp32 -> bf16 conversion, 4 elems/thread
// ---------------------------------------------------------------------------
__global__ __launch_bounds__(256) void f32_to_bf16(
    const float* __restrict__ in, ushort* __restrict__ outp) {
  int i = (blockIdx.x * 256 + threadIdx.x) * 4;
  float4 v = *(const float4*)(in + i);
  ushort4 o;
  o.x = f2bf(v.x); o.y = f2bf(v.y); o.z = f2bf(v.z); o.w = f2bf(v.w);
  *(ushort4*)(outp + i) = o;
}

// ---------------------------------------------------------------------------
// MFMA GEMM: out[m,n] = sum_k A[m,k]*Wt[n,k] + bias[n]; A,Wt bf16, out fp32.
// 128x128 tile, BK=32, 256 threads (4 waves, 2x2, each 64x64). m97 pattern.
// ---------------------------------------------------------------------------
#define GT 128
#define GBK 32
__global__ __launch_bounds__(256) void gemm_mfma_bt(
    const ushort* __restrict__ A, const ushort* __restrict__ Wt,
    const float* __restrict__ bias, float* __restrict__ out,
    int N, int K) {
  __shared__ ushort As[GT * GBK] __attribute__((aligned(16)));
  __shared__ ushort Bs[GT * GBK] __attribute__((aligned(16)));
  int tid = threadIdx.x;
  int lane = tid & 63;
  int lrow = lane & 15, quad = lane >> 4;
  int wave = tid >> 6;
  int wr = wave >> 1, wc = wave & 1;     // 2x2 wave grid
  int row0 = blockIdx.y * GT;
  int col0 = blockIdx.x * GT;

  // staging chunks: thread stages 16B chunks c0,c1 of each tile.
  // chunk c: row=c/4, col=(c%4)*8; LDS dest = flat c*8 elems (lane-contiguous)
  const int c0 = tid, c1 = tid + 256;
  const size_t ga0 = (size_t)(row0 + (c0 >> 2)) * K + ((c0 & 3) * 8);
  const size_t ga1 = (size_t)(row0 + (c1 >> 2)) * K + ((c1 & 3) * 8);
  const size_t gb0 = (size_t)(col0 + (c0 >> 2)) * K + ((c0 & 3) * 8);
  const size_t gb1 = (size_t)(col0 + (c1 >> 2)) * K + ((c1 & 3) * 8);

  f32x4 acc[4][4];
#pragma unroll
  for (int i = 0; i < 4; i++)
#pragma unroll
    for (int j = 0; j < 4; j++) acc[i][j] = (f32x4){0.f, 0.f, 0.f, 0.f};

  for (int k0 = 0; k0 < K; k0 += GBK) {
    async_load16(A + ga0 + k0, &As[c0 * 8]);
    async_load16(A + ga1 + k0, &As[c1 * 8]);
    async_load16(Wt + gb0 + k0, &Bs[c0 * 8]);
    async_load16(Wt + gb1 + k0, &Bs[c1 * 8]);
    __syncthreads();   // drains vmcnt (global_load_lds) + lgkm
    bf16x8 af[4], bfr[4];
#pragma unroll
    for (int i = 0; i < 4; i++)
      af[i] = *(const bf16x8*)&As[(wr * 64 + i * 16 + lrow) * GBK + quad * 8];
#pragma unroll
    for (int j = 0; j < 4; j++)
      bfr[j] = *(const bf16x8*)&Bs[(wc * 64 + j * 16 + lrow) * GBK + quad * 8];
#pragma unroll
    for (int i = 0; i < 4; i++)
#pragma unroll
      for (int j = 0; j < 4; j++)
        acc[i][j] = __builtin_amdgcn_mfma_f32_16x16x32_bf16(af[i], bfr[j], acc[i][j], 0, 0, 0);
    __syncthreads();   // all waves done reading LDS before next stage
  }

#pragma unroll
  for (int i = 0; i < 4; i++)
#pragma unroll
    for (int j = 0; j < 4; j++) {
      int n = col0 + wc * 64 + j * 16 + lrow;
      float bn = bias[n];
#pragma unroll
      for (int r = 0; r < 4; r++) {
        int m = row0 + wr * 64 + i * 16 + quad * 4 + r;
        out[(size_t)m * N + n] = acc[i][j][r] + bn;
      }
    }
}

// ---------------------------------------------------------------------------
// RoPE + transpose (B,T,H,D) fp32 -> (B,H,T,D) bf16.
// ---------------------------------------------------------------------------
__global__ __launch_bounds__(256) void rope_transpose_bf16(
    const float* __restrict__ in, ushort* __restrict__ outp) {
  int idx = blockIdx.x * blockDim.x + threadIdx.x;  // B*H*T*32 total
  int i = idx & 31;
  int t = (idx >> 5) & (T - 1);
  int h = (idx >> 16) & (H - 1);
  int b = idx >> 20;
  const float* src = in + ((size_t)b * T + t) * C + h * D;
  float xr = src[i];
  float xi = src[i + 32];
  float alpha = powf(10000.f, -(float)i / 32.f);
  float ang = (float)t * alpha;
  float c = cosf(ang), s = sinf(ang);
  ushort* dst = outp + (((size_t)b * H + h) * T + t) * D;
  dst[i]      = f2bf(xr * c - xi * s);
  dst[i + 32] = f2bf(xr * s + xi * c);
}

// ---------------------------------------------------------------------------
// V transpose: (B,T,H,D) fp32 -> (B,H,D,T) bf16
// ---------------------------------------------------------------------------
__global__ __launch_bounds__(256) void transpose_vt(
    const float* __restrict__ in, ushort* __restrict__ outp) {
  __shared__ ushort tile[64][65];
  int bh = blockIdx.y;
  int b = bh >> 4, h = bh & 15;
  int t0 = blockIdx.x * 64;
#pragma unroll
  for (int i = 0; i < 16; i++) {
    int lin = threadIdx.x + i * 256;
    int d = lin & 63, tq = lin >> 6;
    tile[d][tq] = f2bf(in[((size_t)b * T + t0 + tq) * C + h * D + d]);
  }
  __syncthreads();
#pragma unroll
  for (int i = 0; i < 16; i++) {
    int lin = threadIdx.x + i * 256;
    int tq = lin & 63, d = lin >> 6;
    outp[((size_t)bh * D + d) * T + t0 + tq] = tile[d][tq];
  }
}

// ---------------------------------------------------------------------------
// MFMA flash attention. One wave per 16-query tile; 4 waves/block = same
// q-tile, 4 different (b,h). Output bf16 (B,T,C).
// ---------------------------------------------------------------------------
__global__ __launch_bounds__(256) void attn_mfma(
    const ushort* __restrict__ qb, const ushort* __restrict__ kb,
    const ushort* __restrict__ vtb, ushort* __restrict__ y) {
  int wave = threadIdx.x >> 6, lane = threadIdx.x & 63;
  int lrow = lane & 15, quad = lane >> 4;
  int qt = blockIdx.x;
  int bh = blockIdx.y * 4 + wave;
  int b = bh >> 4, h = bh & 15;
  int q0 = qt * 16;

  __shared__ ushort Pall[4][16 * 32];
  ushort* P = Pall[wave];

  const ushort* qptr = qb + ((size_t)bh * T + q0 + lrow) * D + quad * 8;
  bf16x8 qa0 = *(const bf16x8*)qptr;
  bf16x8 qa1 = *(const bf16x8*)(qptr + 32);

  f32x4 o0 = {0.f, 0.f, 0.f, 0.f}, o1 = o0, o2 = o0, o3 = o0;
  float mrow[4], lsum[4];
#pragma unroll
  for (int r = 0; r < 4; r++) { mrow[r] = -1e30f; lsum[r] = 0.f; }

  int nk = (q0 + 16 + 31) / 32;
  for (int kt = 0; kt < nk; kt++) {
    int s0 = kt * 32;
    const ushort* kp = kb + ((size_t)bh * T + s0 + lrow) * D + quad * 8;
    bf16x8 k00 = *(const bf16x8*)kp;
    bf16x8 k01 = *(const bf16x8*)(kp + 32);
    bf16x8 k10 = *(const bf16x8*)(kp + 16 * D);
    bf16x8 k11 = *(const bf16x8*)(kp + 16 * D + 32);
    f32x4 z = {0.f, 0.f, 0.f, 0.f};
    f32x4 s_0 = __builtin_amdgcn_mfma_f32_16x16x32_bf16(qa0, k00, z, 0, 0, 0);
    s_0 = __builtin_amdgcn_mfma_f32_16x16x32_bf16(qa1, k01, s_0, 0, 0, 0);
    f32x4 s_1 = __builtin_amdgcn_mfma_f32_16x16x32_bf16(qa0, k10, z, 0, 0, 0);
    s_1 = __builtin_amdgcn_mfma_f32_16x16x32_bf16(qa1, k11, s_1, 0, 0, 0);

#pragma unroll
    for (int r = 0; r < 4; r++) {
      int qrow = q0 + quad * 4 + r;
      float sv0 = s_0[r] * 0.125f;
      float sv1 = s_1[r] * 0.125f;
      if (s0 + lrow > qrow) sv0 = -1e30f;
      if (s0 + 16 + lrow > qrow) sv1 = -1e30f;
      float cm = fmaxf(sv0, sv1);
      cm = fmaxf(cm, __shfl_xor(cm, 1));
      cm = fmaxf(cm, __shfl_xor(cm, 2));
      cm = fmaxf(cm, __shfl_xor(cm, 4));
      cm = fmaxf(cm, __shfl_xor(cm, 8));
      float mn = fmaxf(mrow[r], cm);
      float alpha = __expf(mrow[r] - mn);
      mrow[r] = mn;
      float p0 = __expf(sv0 - mn), p1 = __expf(sv1 - mn);
      float rs = p0 + p1;
      rs += __shfl_xor(rs, 1);
      rs += __shfl_xor(rs, 2);
      rs += __shfl_xor(rs, 4);
      rs += __shfl_xor(rs, 8);
      lsum[r] = lsum[r] * alpha + rs;
      o0[r] *= alpha; o1[r] *= alpha; o2[r] *= alpha; o3[r] *= alpha;
      P[(quad * 4 + r) * 32 + lrow] = f2bf(p0);
      P[(quad * 4 + r) * 32 + 16 + lrow] = f2bf(p1);
    }
    __syncthreads();
    bf16x8 pa = *(const bf16x8*)&P[lrow * 32 + quad * 8];
    __syncthreads();
    const ushort* vp = vtb + ((size_t)bh * D + lrow) * T + s0 + quad * 8;
    o0 = __builtin_amdgcn_mfma_f32_16x16x32_bf16(pa, *(const bf16x8*)(vp), o0, 0, 0, 0);
    o1 = __builtin_amdgcn_mfma_f32_16x16x32_bf16(pa, *(const bf16x8*)(vp + 16 * T), o1, 0, 0, 0);
    o2 = __builtin_amdgcn_mfma_f32_16x16x32_bf16(pa, *(const bf16x8*)(vp + 32 * T), o2, 0, 0, 0);
    o3 = __builtin_amdgcn_mfma_f32_16x16x32_bf16(pa, *(const bf16x8*)(vp + 48 * T), o3, 0, 0, 0);
  }

#pragma unroll
  for (int r = 0; r < 4; r++) {
    float inv = 1.f / lsum[r];
    int qrow = q0 + quad * 4 + r;
    ushort* dst = y + ((size_t)b * T + qrow) * C + h * D + lrow;
    dst[0]  = f2bf(o0[r] * inv);
    dst[16] = f2bf(o1[r] * inv);
    dst[32] = f2bf(o2[r] * inv);
    dst[48] = f2bf(o3[r] * inv);
  }
}

// ---------------------------------------------------------------------------
extern "C" void kernel_launch(void* const* d_in, const int* in_sizes, int n_in,
                              void* d_out, int out_size, void* d_ws, size_t ws_size,
                              hipStream_t stream) {
  const float* x  = (const float*)d_in[0];
  const float* wq = (const float*)d_in[1];
  const float* bq = (const float*)d_in[2];
  const float* wk = (const float*)d_in[3];
  const float* bk = (const float*)d_in[4];
  const float* wv = (const float*)d_in[5];
  const float* bv = (const float*)d_in[6];
  const float* wp = (const float*)d_in[7];
  const float* bp = (const float*)d_in[8];
  float* out = (float*)d_out;

  float* tmp0 = (float*)d_ws;             // (B,T,C) fp32 scratch (32 MB)
  ushort* qb  = (ushort*)(tmp0 + BTC);    // (B,H,T,D) bf16
  ushort* kb  = qb + BTC;
  ushort* vtb = kb + BTC;                 // (B,H,D,T) bf16
  ushort* xb  = vtb + BTC;                // (B,T,C) bf16
  ushort* yb  = xb + BTC;                 // (B,T,C) bf16
  ushort* wqb = yb + BTC;                 // (C,C) bf16 each
  ushort* wkb = wqb + (size_t)C * C;
  ushort* wvb = wkb + (size_t)C * C;
  ushort* wpb = wvb + (size_t)C * C;

  int conv_x_blocks = (int)(BTC / 1024);        // 8192
  int conv_w_blocks = (C * C) / 1024;           // 1024
  dim3 gemm_grid(C / GT, M / GT);               // (8, 64)
  int rope_blocks = (B * H * T * 32) / 256;     // 16384
  dim3 vt_grid(T / 64, B * H);                  // (32, 64)
  dim3 attn_grid(T / 16, (B * H) / 4);          // (128, 16)

  f32_to_bf16<<<conv_x_blocks, 256, 0, stream>>>(x, xb);
  f32_to_bf16<<<conv_w_blocks, 256, 0, stream>>>(wq, wqb);
  f32_to_bf16<<<conv_w_blocks, 256, 0, stream>>>(wk, wkb);
  f32_to_bf16<<<conv_w_blocks, 256, 0, stream>>>(wv, wvb);
  f32_to_bf16<<<conv_w_blocks, 256, 0, stream>>>(wp, wpb);

  gemm_mfma_bt<<<gemm_grid, 256, 0, stream>>>(xb, wqb, bq, tmp0, C, C);
  rope_transpose_bf16<<<rope_blocks, 256, 0, stream>>>(tmp0, qb);
  gemm_mfma_bt<<<gemm_grid, 256, 0, stream>>>(xb, wkb, bk, tmp0, C, C);
  rope_transpose_bf16<<<rope_blocks, 256, 0, stream>>>(tmp0, kb);
  gemm_mfma_bt<<<gemm_grid, 256, 0, stream>>>(xb, wvb, bv, tmp0, C, C);
  transpose_vt<<<vt_grid, 256, 0, stream>>>(tmp0, vtb);
  attn_mfma<<<attn_grid, 256, 0, stream>>>(qb, kb, vtb, yb);
  gemm_mfma_bt<<<gemm_grid, 256, 0, stream>>>(yb, wpb, bp, out, C, C);
}

// Round 4
// 529.507 us; speedup vs baseline: 19.9062x; 1.2333x over previous
//
#include <hip/hip_runtime.h>
#include <math.h>

constexpr int B = 4, T = 2048, C = 1024, H = 16, D = 64;
constexpr int M = B * T;            // 8192 GEMM rows
constexpr size_t BTC = (size_t)B * T * C;

typedef short bf16x8 __attribute__((ext_vector_type(8)));
typedef float f32x4 __attribute__((ext_vector_type(4)));

__device__ inline ushort f2bf(float f) {
  union { float f; unsigned u; } cv; cv.f = f;
  unsigned u = cv.u;
  u += 0x7fffu + ((u >> 16) & 1u);   // round-to-nearest-even
  return (ushort)(u >> 16);
}
__device__ inline ushort f2bfr(float f) {  // fast round-to-nearest (P only)
  union { float f; unsigned u; } cv; cv.f = f;
  return (ushort)((cv.u + 0x8000u) >> 16);
}

__device__ inline void async_load16(const void* g, void* l) {
  __builtin_amdgcn_global_load_lds(
      (const __attribute__((address_space(1))) void*)g,
      (__attribute__((address_space(3))) void*)l, 16, 0, 0);
}

// ---------------------------------------------------------------------------
// fp32 -> bf16 conversion, 4 elems/thread
// ---------------------------------------------------------------------------
__global__ __launch_bounds__(256) void f32_to_bf16(
    const float* __restrict__ in, ushort* __restrict__ outp) {
  int i = (blockIdx.x * 256 + threadIdx.x) * 4;
  float4 v = *(const float4*)(in + i);
  ushort4 o;
  o.x = f2bf(v.x); o.y = f2bf(v.y); o.z = f2bf(v.z); o.w = f2bf(v.w);
  *(ushort4*)(outp + i) = o;
}

// ---------------------------------------------------------------------------
// MFMA GEMM (m97 pattern): out = A @ Wt^T + bias, bf16 in, fp32 out
// ---------------------------------------------------------------------------
#define GT 128
#define GBK 32
__global__ __launch_bounds__(256) void gemm_mfma_bt(
    const ushort* __restrict__ A, const ushort* __restrict__ Wt,
    const float* __restrict__ bias, float* __restrict__ out,
    int N, int K) {
  __shared__ ushort As[GT * GBK] __attribute__((aligned(16)));
  __shared__ ushort Bs[GT * GBK] __attribute__((aligned(16)));
  int tid = threadIdx.x;
  int lane = tid & 63;
  int lrow = lane & 15, quad = lane >> 4;
  int wave = tid >> 6;
  int wr = wave >> 1, wc = wave & 1;
  int row0 = blockIdx.y * GT;
  int col0 = blockIdx.x * GT;

  const int c0 = tid, c1 = tid + 256;
  const size_t ga0 = (size_t)(row0 + (c0 >> 2)) * K + ((c0 & 3) * 8);
  const size_t ga1 = (size_t)(row0 + (c1 >> 2)) * K + ((c1 & 3) * 8);
  const size_t gb0 = (size_t)(col0 + (c0 >> 2)) * K + ((c0 & 3) * 8);
  const size_t gb1 = (size_t)(col0 + (c1 >> 2)) * K + ((c1 & 3) * 8);

  f32x4 acc[4][4];
#pragma unroll
  for (int i = 0; i < 4; i++)
#pragma unroll
    for (int j = 0; j < 4; j++) acc[i][j] = (f32x4){0.f, 0.f, 0.f, 0.f};

  for (int k0 = 0; k0 < K; k0 += GBK) {
    async_load16(A + ga0 + k0, &As[c0 * 8]);
    async_load16(A + ga1 + k0, &As[c1 * 8]);
    async_load16(Wt + gb0 + k0, &Bs[c0 * 8]);
    async_load16(Wt + gb1 + k0, &Bs[c1 * 8]);
    __syncthreads();
    bf16x8 af[4], bfr[4];
#pragma unroll
    for (int i = 0; i < 4; i++)
      af[i] = *(const bf16x8*)&As[(wr * 64 + i * 16 + lrow) * GBK + quad * 8];
#pragma unroll
    for (int j = 0; j < 4; j++)
      bfr[j] = *(const bf16x8*)&Bs[(wc * 64 + j * 16 + lrow) * GBK + quad * 8];
#pragma unroll
    for (int i = 0; i < 4; i++)
#pragma unroll
      for (int j = 0; j < 4; j++)
        acc[i][j] = __builtin_amdgcn_mfma_f32_16x16x32_bf16(af[i], bfr[j], acc[i][j], 0, 0, 0);
    __syncthreads();
  }

#pragma unroll
  for (int i = 0; i < 4; i++)
#pragma unroll
    for (int j = 0; j < 4; j++) {
      int n = col0 + wc * 64 + j * 16 + lrow;
      float bn = bias[n];
#pragma unroll
      for (int r = 0; r < 4; r++) {
        int m = row0 + wr * 64 + i * 16 + quad * 4 + r;
        out[(size_t)m * N + n] = acc[i][j][r] + bn;
      }
    }
}

// ---------------------------------------------------------------------------
// RoPE + transpose (B,T,H,D) fp32 -> (B,H,T,D) bf16, with scale folding
// ---------------------------------------------------------------------------
__global__ __launch_bounds__(256) void rope_transpose_bf16(
    const float* __restrict__ in, ushort* __restrict__ outp, float scale) {
  int idx = blockIdx.x * blockDim.x + threadIdx.x;
  int i = idx & 31;
  int t = (idx >> 5) & (T - 1);
  int h = (idx >> 16) & (H - 1);
  int b = idx >> 20;
  const float* src = in + ((size_t)b * T + t) * C + h * D;
  float xr = src[i];
  float xi = src[i + 32];
  float alpha = powf(10000.f, -(float)i / 32.f);
  float ang = (float)t * alpha;
  float c = cosf(ang), s = sinf(ang);
  ushort* dst = outp + (((size_t)b * H + h) * T + t) * D;
  dst[i]      = f2bf((xr * c - xi * s) * scale);
  dst[i + 32] = f2bf((xr * s + xi * c) * scale);
}

// ---------------------------------------------------------------------------
// V transpose: (B,T,H,D) fp32 -> (B,H,D,T) bf16
// ---------------------------------------------------------------------------
__global__ __launch_bounds__(256) void transpose_vt(
    const float* __restrict__ in, ushort* __restrict__ outp) {
  __shared__ ushort tile[64][65];
  int bh = blockIdx.y;
  int b = bh >> 4, h = bh & 15;
  int t0 = blockIdx.x * 64;
#pragma unroll
  for (int i = 0; i < 16; i++) {
    int lin = threadIdx.x + i * 256;
    int d = lin & 63, tq = lin >> 6;
    tile[d][tq] = f2bf(in[((size_t)b * T + t0 + tq) * C + h * D + d]);
  }
  __syncthreads();
#pragma unroll
  for (int i = 0; i < 16; i++) {
    int lin = threadIdx.x + i * 256;
    int tq = lin & 63, d = lin >> 6;
    outp[((size_t)bh * D + d) * T + t0 + tq] = tile[d][tq];
  }
}

// ---------------------------------------------------------------------------
// MFMA flash attention v2: S^T layout, 64-key tiles, no barriers.
// Each wave: 16 queries vs full causal K range for one (b,h).
// S^T = K.Q^T -> keys on C-rows (in-lane reduction), queries on C-cols.
// ---------------------------------------------------------------------------
constexpr int PS = 72;  // padded P row stride (elems): conflict-free b64/b128

template <bool MASKED>
__device__ __forceinline__ void attn_step(
    int s0, const ushort* kbase, const ushort* vbase,
    bf16x8 qf0, bf16x8 qf1, ushort* P, int lrow, int quad, int qabs,
    f32x4 (&o)[4], float& mrun, float& lrun) {
  // K frags: A[m=key_local][k=d]
  bf16x8 kf[4][2];
#pragma unroll
  for (int kt = 0; kt < 4; kt++) {
    const ushort* kp = kbase + (size_t)(s0 + kt * 16) * D;
    kf[kt][0] = *(const bf16x8*)kp;
    kf[kt][1] = *(const bf16x8*)(kp + 32);
  }
  // V frags (independent of softmax — issue early): A[m=d_local][k=s]
  bf16x8 vf[4][2];
#pragma unroll
  for (int dsub = 0; dsub < 4; dsub++) {
    const ushort* vp = vbase + (size_t)(dsub * 16) * T + s0;
    vf[dsub][0] = *(const bf16x8*)vp;
    vf[dsub][1] = *(const bf16x8*)(vp + 32);
  }
  // S^T = K . Q^T  (scale pre-folded into Q)
  f32x4 st[4];
#pragma unroll
  for (int kt = 0; kt < 4; kt++) {
    f32x4 z = {0.f, 0.f, 0.f, 0.f};
    st[kt] = __builtin_amdgcn_mfma_f32_16x16x32_bf16(kf[kt][0], qf0, z, 0, 0, 0);
    st[kt] = __builtin_amdgcn_mfma_f32_16x16x32_bf16(kf[kt][1], qf1, st[kt], 0, 0, 0);
  }
  if (MASKED) {
    int qrel = qabs - s0;
#pragma unroll
    for (int kt = 0; kt < 4; kt++)
#pragma unroll
      for (int r = 0; r < 4; r++)
        if (kt * 16 + quad * 4 + r > qrel) st[kt][r] = -1e30f;
  }
  // online softmax: reduce over keys = 15 in-lane + 2 shuffles
  float cmax = st[0][0];
#pragma unroll
  for (int kt = 0; kt < 4; kt++)
#pragma unroll
    for (int r = 0; r < 4; r++) cmax = fmaxf(cmax, st[kt][r]);
  cmax = fmaxf(cmax, __shfl_xor(cmax, 16));
  cmax = fmaxf(cmax, __shfl_xor(cmax, 32));
  float mn = fmaxf(mrun, cmax);
  float alpha = __expf(mrun - mn);
  mrun = mn;
  float rsum = 0.f;
#pragma unroll
  for (int kt = 0; kt < 4; kt++)
#pragma unroll
    for (int r = 0; r < 4; r++) {
      float p = __expf(st[kt][r] - mn);
      st[kt][r] = p;
      rsum += p;
    }
  rsum += __shfl_xor(rsum, 16);
  rsum += __shfl_xor(rsum, 32);
  lrun = lrun * alpha + rsum;
#pragma unroll
  for (int dsub = 0; dsub < 4; dsub++)
#pragma unroll
    for (int r = 0; r < 4; r++) o[dsub][r] *= alpha;
  // pack P^T into LDS as [q][key] for B-frag reads
#pragma unroll
  for (int kt = 0; kt < 4; kt++) {
    ushort4 pk;
    pk.x = f2bfr(st[kt][0]); pk.y = f2bfr(st[kt][1]);
    pk.z = f2bfr(st[kt][2]); pk.w = f2bfr(st[kt][3]);
    *(ushort4*)&P[lrow * PS + kt * 16 + quad * 4] = pk;
  }
  asm volatile("" ::: "memory");   // keep ds_read after ds_write (in-wave, in-order DS)
  bf16x8 pf0 = *(const bf16x8*)&P[lrow * PS + quad * 8];
  bf16x8 pf1 = *(const bf16x8*)&P[lrow * PS + 32 + quad * 8];
  // O^T += Vt . P^T
#pragma unroll
  for (int dsub = 0; dsub < 4; dsub++) {
    o[dsub] = __builtin_amdgcn_mfma_f32_16x16x32_bf16(vf[dsub][0], pf0, o[dsub], 0, 0, 0);
    o[dsub] = __builtin_amdgcn_mfma_f32_16x16x32_bf16(vf[dsub][1], pf1, o[dsub], 0, 0, 0);
  }
}

__global__ __launch_bounds__(256) void attn_mfma2(
    const ushort* __restrict__ qb, const ushort* __restrict__ kb,
    const ushort* __restrict__ vtb, ushort* __restrict__ y) {
  __shared__ ushort Pall[4][16 * PS];
  int wave = threadIdx.x >> 6, lane = threadIdx.x & 63;
  int lrow = lane & 15, quad = lane >> 4;
  int wid = blockIdx.x * 4 + wave;
  int qt = 127 - (wid >> 6);     // descending work: longest blocks first
  int bh = wid & 63;
  int b = bh >> 4, h = bh & 15;
  int q0 = qt * 16;
  ushort* P = Pall[wave];

  // Q as B-operand frags: B[k=d][n=q] from row-major Q
  const ushort* qptr = qb + ((size_t)bh * T + q0 + lrow) * D + quad * 8;
  bf16x8 qf0 = *(const bf16x8*)qptr;
  bf16x8 qf1 = *(const bf16x8*)(qptr + 32);

  const ushort* kbase = kb + ((size_t)bh * T + lrow) * D + quad * 8;
  const ushort* vbase = vtb + ((size_t)bh * D + lrow) * T + quad * 8;

  f32x4 o[4];
#pragma unroll
  for (int dsub = 0; dsub < 4; dsub++) o[dsub] = (f32x4){0.f, 0.f, 0.f, 0.f};
  float mrun = -1e30f, lrun = 0.f;
  int qabs = q0 + lrow;
  int nfull = q0 >> 6;

  for (int it = 0; it < nfull; it++)
    attn_step<false>(it * 64, kbase, vbase, qf0, qf1, P, lrow, quad, qabs, o, mrun, lrun);
  attn_step<true>(nfull * 64, kbase, vbase, qf0, qf1, P, lrow, quad, qabs, o, mrun, lrun);

  float inv = 1.f / lrun;
#pragma unroll
  for (int dsub = 0; dsub < 4; dsub++) {
    ushort4 pk;
    pk.x = f2bf(o[dsub][0] * inv); pk.y = f2bf(o[dsub][1] * inv);
    pk.z = f2bf(o[dsub][2] * inv); pk.w = f2bf(o[dsub][3] * inv);
    *(ushort4*)(y + ((size_t)b * T + q0 + lrow) * C + h * D + dsub * 16 + quad * 4) = pk;
  }
}

// ---------------------------------------------------------------------------
extern "C" void kernel_launch(void* const* d_in, const int* in_sizes, int n_in,
                              void* d_out, int out_size, void* d_ws, size_t ws_size,
                              hipStream_t stream) {
  const float* x  = (const float*)d_in[0];
  const float* wq = (const float*)d_in[1];
  const float* bq = (const float*)d_in[2];
  const float* wk = (const float*)d_in[3];
  const float* bk = (const float*)d_in[4];
  const float* wv = (const float*)d_in[5];
  const float* bv = (const float*)d_in[6];
  const float* wp = (const float*)d_in[7];
  const float* bp = (const float*)d_in[8];
  float* out = (float*)d_out;

  float* tmp0 = (float*)d_ws;             // (B,T,C) fp32 scratch
  ushort* qb  = (ushort*)(tmp0 + BTC);    // (B,H,T,D) bf16 (pre-scaled 1/8)
  ushort* kb  = qb + BTC;
  ushort* vtb = kb + BTC;                 // (B,H,D,T) bf16
  ushort* xb  = vtb + BTC;                // (B,T,C) bf16
  ushort* yb  = xb + BTC;                 // (B,T,C) bf16
  ushort* wqb = yb + BTC;
  ushort* wkb = wqb + (size_t)C * C;
  ushort* wvb = wkb + (size_t)C * C;
  ushort* wpb = wvb + (size_t)C * C;

  int conv_x_blocks = (int)(BTC / 1024);
  int conv_w_blocks = (C * C) / 1024;
  dim3 gemm_grid(C / GT, M / GT);
  int rope_blocks = (B * H * T * 32) / 256;
  dim3 vt_grid(T / 64, B * H);
  int attn_blocks = (B * H * T / 16) / 4;   // 2048

  f32_to_bf16<<<conv_x_blocks, 256, 0, stream>>>(x, xb);
  f32_to_bf16<<<conv_w_blocks, 256, 0, stream>>>(wq, wqb);
  f32_to_bf16<<<conv_w_blocks, 256, 0, stream>>>(wk, wkb);
  f32_to_bf16<<<conv_w_blocks, 256, 0, stream>>>(wv, wvb);
  f32_to_bf16<<<conv_w_blocks, 256, 0, stream>>>(wp, wpb);

  gemm_mfma_bt<<<gemm_grid, 256, 0, stream>>>(xb, wqb, bq, tmp0, C, C);
  rope_transpose_bf16<<<rope_blocks, 256, 0, stream>>>(tmp0, qb, 0.125f);
  gemm_mfma_bt<<<gemm_grid, 256, 0, stream>>>(xb, wkb, bk, tmp0, C, C);
  rope_transpose_bf16<<<rope_blocks, 256, 0, stream>>>(tmp0, kb, 1.0f);
  gemm_mfma_bt<<<gemm_grid, 256, 0, stream>>>(xb, wvb, bv, tmp0, C, C);
  transpose_vt<<<vt_grid, 256, 0, stream>>>(tmp0, vtb);
  attn_mfma2<<<attn_blocks, 256, 0, stream>>>(qb, kb, vtb, yb);
  gemm_mfma_bt<<<gemm_grid, 256, 0, stream>>>(yb, wpb, bp, out, C, C);
}

// Round 5
// 330.424 us; speedup vs baseline: 31.8999x; 1.6025x over previous
//
#include <hip/hip_runtime.h>
#include <math.h>

constexpr int B = 4, T = 2048, C = 1024, H = 16, D = 64;
constexpr int M = B * T;
constexpr size_t BTC = (size_t)B * T * C;

typedef short bf16x8 __attribute__((ext_vector_type(8)));
typedef float f32x4 __attribute__((ext_vector_type(4)));

__device__ inline ushort f2bf(float f) {
  union { float f; unsigned u; } cv; cv.f = f;
  unsigned u = cv.u;
  u += 0x7fffu + ((u >> 16) & 1u);   // round-to-nearest-even
  return (ushort)(u >> 16);
}
__device__ inline ushort f2bfr(float f) {  // fast round (P only)
  union { float f; unsigned u; } cv; cv.f = f;
  return (ushort)((cv.u + 0x8000u) >> 16);
}
__device__ inline float bf2f(ushort u) {
  union { unsigned u; float f; } cv; cv.u = ((unsigned)u) << 16; return cv.f;
}

__device__ inline void async_load16(const void* g, void* l) {
  __builtin_amdgcn_global_load_lds(
      (const __attribute__((address_space(1))) void*)g,
      (__attribute__((address_space(3))) void*)l, 16, 0, 0);
}

// ---------------------------------------------------------------------------
// fp32 -> bf16 conversion, 4 elems/thread
// ---------------------------------------------------------------------------
__global__ __launch_bounds__(256) void f32_to_bf16(
    const float* __restrict__ in, ushort* __restrict__ outp) {
  int i = (blockIdx.x * 256 + threadIdx.x) * 4;
  float4 v = *(const float4*)(in + i);
  ushort4 o;
  o.x = f2bf(v.x); o.y = f2bf(v.y); o.z = f2bf(v.z); o.w = f2bf(v.w);
  *(ushort4*)(outp + i) = o;
}

// ---------------------------------------------------------------------------
// MFMA GEMM: out = A @ Wt^T + bias. bf16 in; out fp32 or bf16 (template).
// 128x128 tile, BK=32, XOR-swizzled LDS staging (2-way banks instead of 8).
// Bias selected per 1024-col segment (QKV fused GEMM).
// ---------------------------------------------------------------------------
#define GT 128
#define GBK 32
template <bool BF16OUT>
__global__ __launch_bounds__(256) void gemm_mfma_bt(
    const ushort* __restrict__ A, const ushort* __restrict__ Wt,
    const float* __restrict__ b0, const float* __restrict__ b1,
    const float* __restrict__ b2, void* __restrict__ outp,
    int N, int K) {
  __shared__ ushort As[GT * GBK] __attribute__((aligned(16)));
  __shared__ ushort Bs[GT * GBK] __attribute__((aligned(16)));
  int tid = threadIdx.x;
  int lane = tid & 63;
  int lrow = lane & 15, quad = lane >> 4;
  int wave = tid >> 6;
  int wr = wave >> 1, wc = wave & 1;
  int row0 = blockIdx.y * GT;
  int col0 = blockIdx.x * GT;
  const float* bias = (col0 < 1024) ? b0 : (col0 < 2048) ? b1 : b2;

  // staging: chunk c -> LDS flat c*8 elems; global col-chunk XOR-swizzled
  int c0 = tid, c1 = tid + 256;
  int r0s = c0 >> 2, g0 = ((c0 & 3) ^ ((r0s >> 1) & 3)) * 8;
  int r1s = c1 >> 2, g1 = ((c1 & 3) ^ ((r1s >> 1) & 3)) * 8;
  const size_t ga0 = (size_t)(row0 + r0s) * K + g0;
  const size_t ga1 = (size_t)(row0 + r1s) * K + g1;
  const size_t gb0 = (size_t)(col0 + r0s) * K + g0;
  const size_t gb1 = (size_t)(col0 + r1s) * K + g1;
  int sw = (quad ^ ((lrow >> 1) & 3)) * 8;   // swizzled read chunk offset

  f32x4 acc[4][4];
#pragma unroll
  for (int i = 0; i < 4; i++)
#pragma unroll
    for (int j = 0; j < 4; j++) acc[i][j] = (f32x4){0.f, 0.f, 0.f, 0.f};

  for (int k0 = 0; k0 < K; k0 += GBK) {
    async_load16(A + ga0 + k0, &As[c0 * 8]);
    async_load16(A + ga1 + k0, &As[c1 * 8]);
    async_load16(Wt + gb0 + k0, &Bs[c0 * 8]);
    async_load16(Wt + gb1 + k0, &Bs[c1 * 8]);
    __syncthreads();
    bf16x8 af[4], bfr[4];
#pragma unroll
    for (int i = 0; i < 4; i++)
      af[i] = *(const bf16x8*)&As[(wr * 64 + i * 16 + lrow) * GBK + sw];
#pragma unroll
    for (int j = 0; j < 4; j++)
      bfr[j] = *(const bf16x8*)&Bs[(wc * 64 + j * 16 + lrow) * GBK + sw];
#pragma unroll
    for (int i = 0; i < 4; i++)
#pragma unroll
      for (int j = 0; j < 4; j++)
        acc[i][j] = __builtin_amdgcn_mfma_f32_16x16x32_bf16(af[i], bfr[j], acc[i][j], 0, 0, 0);
    __syncthreads();
  }

#pragma unroll
  for (int i = 0; i < 4; i++)
#pragma unroll
    for (int j = 0; j < 4; j++) {
      int n = col0 + wc * 64 + j * 16 + lrow;
      float bn = bias[n & 1023];
#pragma unroll
      for (int r = 0; r < 4; r++) {
        int m = row0 + wr * 64 + i * 16 + quad * 4 + r;
        float v = acc[i][j][r] + bn;
        if (BF16OUT) ((ushort*)outp)[(size_t)m * N + n] = f2bf(v);
        else         ((float*)outp)[(size_t)m * N + n] = v;
      }
    }
}

// ---------------------------------------------------------------------------
// RoPE + transpose (B,T,3C) bf16 (ptr pre-offset to Q or K) -> (B,H,T,D) bf16
// ---------------------------------------------------------------------------
__global__ __launch_bounds__(256) void rope_transpose_bf16(
    const ushort* __restrict__ in, ushort* __restrict__ outp, float scale) {
  int idx = blockIdx.x * blockDim.x + threadIdx.x;
  int i = idx & 31;
  int t = (idx >> 5) & (T - 1);
  int h = (idx >> 16) & (H - 1);
  int b = idx >> 20;
  const ushort* src = in + ((size_t)b * T + t) * (3 * C) + h * D;
  float xr = bf2f(src[i]);
  float xi = bf2f(src[i + 32]);
  float alpha = powf(10000.f, -(float)i / 32.f);
  float ang = (float)t * alpha;
  float c = cosf(ang), s = sinf(ang);
  ushort* dst = outp + (((size_t)b * H + h) * T + t) * D;
  dst[i]      = f2bf((xr * c - xi * s) * scale);
  dst[i + 32] = f2bf((xr * s + xi * c) * scale);
}

// ---------------------------------------------------------------------------
// V transpose: (B,T,3C) bf16 (ptr pre-offset to V) -> (B,H,D,T) bf16
// ---------------------------------------------------------------------------
__global__ __launch_bounds__(256) void transpose_vt(
    const ushort* __restrict__ in, ushort* __restrict__ outp) {
  __shared__ ushort tile[64][65];
  int bh = blockIdx.y;
  int b = bh >> 4, h = bh & 15;
  int t0 = blockIdx.x * 64;
#pragma unroll
  for (int i = 0; i < 16; i++) {
    int lin = threadIdx.x + i * 256;
    int d = lin & 63, tq = lin >> 6;
    tile[d][tq] = in[((size_t)b * T + t0 + tq) * (3 * C) + h * D + d];
  }
  __syncthreads();
#pragma unroll
  for (int i = 0; i < 16; i++) {
    int lin = threadIdx.x + i * 256;
    int tq = lin & 63, d = lin >> 6;
    outp[((size_t)bh * D + d) * T + t0 + tq] = tile[d][tq];
  }
}

// ---------------------------------------------------------------------------
// MFMA flash attention v3 (FA2-style): block = 4 waves, one bh, 64-query
// block; K/V tiles staged in LDS (double-buffered, XOR-swizzled), shared by
// all 4 waves. S^T = K.Q^T layout (softmax reduce mostly in-lane).
// ---------------------------------------------------------------------------
constexpr int PS = 72;  // padded P row stride

__device__ __forceinline__ void stage_kv(
    const ushort* kbh, const ushort* vbh, int s0,
    ushort* Kl, ushort* Vl, int tid) {
#pragma unroll
  for (int i = 0; i < 2; i++) {
    int c = tid + i * 256;              // 0..511 chunk of 64x64 tile
    int r = c >> 3, cc = c & 7;
    int g = (cc ^ (r & 7)) * 8;         // XOR-swizzled source col-chunk
    async_load16(kbh + (size_t)(s0 + r) * D + g, Kl + c * 8);
    async_load16(vbh + (size_t)r * T + s0 + g, Vl + c * 8);
  }
}

template <bool MASKED>
__device__ __forceinline__ void attn_step(
    const ushort* Kl, const ushort* Vl, bf16x8 qf0, bf16x8 qf1,
    ushort* P, int lrow, int quad, int sw0, int sw1, int qrel,
    f32x4 (&o)[4], float& mrun, float& lrun) {
  f32x4 st[4];
#pragma unroll
  for (int kt = 0; kt < 4; kt++) {
    int base = (kt * 16 + lrow) * 64;
    bf16x8 k0 = *(const bf16x8*)&Kl[base + sw0];
    bf16x8 k1 = *(const bf16x8*)&Kl[base + sw1];
    f32x4 z = {0.f, 0.f, 0.f, 0.f};
    st[kt] = __builtin_amdgcn_mfma_f32_16x16x32_bf16(k0, qf0, z, 0, 0, 0);
    st[kt] = __builtin_amdgcn_mfma_f32_16x16x32_bf16(k1, qf1, st[kt], 0, 0, 0);
  }
  if (MASKED) {
#pragma unroll
    for (int kt = 0; kt < 4; kt++)
#pragma unroll
      for (int r = 0; r < 4; r++)
        if (kt * 16 + quad * 4 + r > qrel) st[kt][r] = -1e30f;
  }
  float cmax = st[0][0];
#pragma unroll
  for (int kt = 0; kt < 4; kt++)
#pragma unroll
    for (int r = 0; r < 4; r++) cmax = fmaxf(cmax, st[kt][r]);
  cmax = fmaxf(cmax, __shfl_xor(cmax, 16));
  cmax = fmaxf(cmax, __shfl_xor(cmax, 32));
  float mn = fmaxf(mrun, cmax);
  float alpha = __expf(mrun - mn);
  mrun = mn;
  float rsum = 0.f;
#pragma unroll
  for (int kt = 0; kt < 4; kt++)
#pragma unroll
    for (int r = 0; r < 4; r++) {
      float p = __expf(st[kt][r] - mn);
      st[kt][r] = p;
      rsum += p;
    }
  rsum += __shfl_xor(rsum, 16);
  rsum += __shfl_xor(rsum, 32);
  lrun = lrun * alpha + rsum;
#pragma unroll
  for (int dsub = 0; dsub < 4; dsub++)
#pragma unroll
    for (int r = 0; r < 4; r++) o[dsub][r] *= alpha;
#pragma unroll
  for (int kt = 0; kt < 4; kt++) {
    ushort4 pk;
    pk.x = f2bfr(st[kt][0]); pk.y = f2bfr(st[kt][1]);
    pk.z = f2bfr(st[kt][2]); pk.w = f2bfr(st[kt][3]);
    *(ushort4*)&P[lrow * PS + kt * 16 + quad * 4] = pk;
  }
  asm volatile("" ::: "memory");   // keep ds_read after ds_write (in-wave order)
  bf16x8 pf0 = *(const bf16x8*)&P[lrow * PS + quad * 8];
  bf16x8 pf1 = *(const bf16x8*)&P[lrow * PS + 32 + quad * 8];
#pragma unroll
  for (int dsub = 0; dsub < 4; dsub++) {
    int base = (dsub * 16 + lrow) * 64;
    bf16x8 v0 = *(const bf16x8*)&Vl[base + sw0];
    bf16x8 v1 = *(const bf16x8*)&Vl[base + sw1];
    o[dsub] = __builtin_amdgcn_mfma_f32_16x16x32_bf16(v0, pf0, o[dsub], 0, 0, 0);
    o[dsub] = __builtin_amdgcn_mfma_f32_16x16x32_bf16(v1, pf1, o[dsub], 0, 0, 0);
  }
}

__global__ __launch_bounds__(256) void attn_mfma3(
    const ushort* __restrict__ qb_, const ushort* __restrict__ kb_,
    const ushort* __restrict__ vtb_, ushort* __restrict__ y) {
  __shared__ ushort Kl[2][64 * 64] __attribute__((aligned(16)));
  __shared__ ushort Vl[2][64 * 64] __attribute__((aligned(16)));
  __shared__ ushort Pall[4][16 * PS];
  int tid = threadIdx.x;
  int wave = tid >> 6, lane = tid & 63;
  int lrow = lane & 15, quad = lane >> 4;
  int qbi = 31 - (int)(blockIdx.x >> 6);   // descending: longest first
  int bh = blockIdx.x & 63;
  int b = bh >> 4, h = bh & 15;
  int q0w = qbi * 64 + wave * 16;          // this wave's 16 queries
  ushort* P = Pall[wave];
  const ushort* kbh = kb_ + (size_t)bh * T * D;
  const ushort* vbh = vtb_ + (size_t)bh * D * T;

  const ushort* qptr = qb_ + ((size_t)bh * T + q0w + lrow) * D + quad * 8;
  bf16x8 qf0 = *(const bf16x8*)qptr;
  bf16x8 qf1 = *(const bf16x8*)(qptr + 32);

  int r7 = lrow & 7;
  int sw0 = (quad ^ r7) * 8;
  int sw1 = ((quad + 4) ^ r7) * 8;

  f32x4 o[4];
#pragma unroll
  for (int d = 0; d < 4; d++) o[d] = (f32x4){0.f, 0.f, 0.f, 0.f};
  float mrun = -1e30f, lrun = 0.f;
  int trips = qbi + 1;

  stage_kv(kbh, vbh, 0, Kl[0], Vl[0], tid);
  int it = 0;
  for (; it < trips - 1; ++it) {
    __syncthreads();                        // buf[it&1] ready; prior reads done
    stage_kv(kbh, vbh, (it + 1) * 64, Kl[(it + 1) & 1], Vl[(it + 1) & 1], tid);
    attn_step<false>(Kl[it & 1], Vl[it & 1], qf0, qf1, P, lrow, quad, sw0, sw1,
                     0, o, mrun, lrun);
  }
  __syncthreads();
  attn_step<true>(Kl[it & 1], Vl[it & 1], qf0, qf1, P, lrow, quad, sw0, sw1,
                  wave * 16 + lrow, o, mrun, lrun);

  float inv = 1.f / lrun;
#pragma unroll
  for (int dsub = 0; dsub < 4; dsub++) {
    ushort4 pk;
    pk.x = f2bf(o[dsub][0] * inv); pk.y = f2bf(o[dsub][1] * inv);
    pk.z = f2bf(o[dsub][2] * inv); pk.w = f2bf(o[dsub][3] * inv);
    *(ushort4*)(y + ((size_t)b * T + q0w + lrow) * C + h * D + dsub * 16 + quad * 4) = pk;
  }
}

// ---------------------------------------------------------------------------
extern "C" void kernel_launch(void* const* d_in, const int* in_sizes, int n_in,
                              void* d_out, int out_size, void* d_ws, size_t ws_size,
                              hipStream_t stream) {
  const float* x  = (const float*)d_in[0];
  const float* wq = (const float*)d_in[1];
  const float* bq = (const float*)d_in[2];
  const float* wk = (const float*)d_in[3];
  const float* bk = (const float*)d_in[4];
  const float* wv = (const float*)d_in[5];
  const float* bv = (const float*)d_in[6];
  const float* wp = (const float*)d_in[7];
  const float* bp = (const float*)d_in[8];
  float* out = (float*)d_out;

  ushort* xb    = (ushort*)d_ws;            // (B,T,C)   bf16  16 MB
  ushort* qkvb  = xb + BTC;                 // (B,T,3C)  bf16  48 MB (y aliases)
  ushort* qb    = qkvb + 3 * BTC;           // (B,H,T,D) bf16 (pre-scaled 1/8)
  ushort* kb    = qb + BTC;
  ushort* vtb   = kb + BTC;                 // (B,H,D,T) bf16
  ushort* wqkvb = vtb + BTC;                // (3C,C) bf16
  ushort* wpb   = wqkvb + (size_t)3 * C * C;

  f32_to_bf16<<<(int)(BTC / 1024), 256, 0, stream>>>(x, xb);
  f32_to_bf16<<<(C * C) / 1024, 256, 0, stream>>>(wq, wqkvb);
  f32_to_bf16<<<(C * C) / 1024, 256, 0, stream>>>(wk, wqkvb + (size_t)C * C);
  f32_to_bf16<<<(C * C) / 1024, 256, 0, stream>>>(wv, wqkvb + (size_t)2 * C * C);
  f32_to_bf16<<<(C * C) / 1024, 256, 0, stream>>>(wp, wpb);

  dim3 qkv_grid(3 * C / GT, M / GT);        // (24, 64)
  gemm_mfma_bt<true><<<qkv_grid, 256, 0, stream>>>(
      xb, wqkvb, bq, bk, bv, qkvb, 3 * C, C);

  int rope_blocks = (B * H * T * 32) / 256;
  rope_transpose_bf16<<<rope_blocks, 256, 0, stream>>>(qkvb, qb, 0.125f);
  rope_transpose_bf16<<<rope_blocks, 256, 0, stream>>>(qkvb + C, kb, 1.0f);
  dim3 vt_grid(T / 64, B * H);
  transpose_vt<<<vt_grid, 256, 0, stream>>>(qkvb + 2 * C, vtb);

  attn_mfma3<<<(B * H * T / 64), 256, 0, stream>>>(qb, kb, vtb, qkvb);

  dim3 proj_grid(C / GT, M / GT);           // (8, 64)
  gemm_mfma_bt<false><<<proj_grid, 256, 0, stream>>>(
      qkvb, wpb, bp, bp, bp, out, C, C);
}

// Round 6
// 290.205 us; speedup vs baseline: 36.3207x; 1.1386x over previous
//
#include <hip/hip_runtime.h>
#include <math.h>

constexpr int B = 4, T = 2048, C = 1024, H = 16, D = 64;
constexpr int M = B * T;
constexpr size_t BTC = (size_t)B * T * C;

typedef short bf16x8 __attribute__((ext_vector_type(8)));
typedef float f32x4 __attribute__((ext_vector_type(4)));

__device__ inline ushort f2bf(float f) {
  union { float f; unsigned u; } cv; cv.f = f;
  unsigned u = cv.u;
  u += 0x7fffu + ((u >> 16) & 1u);   // round-to-nearest-even
  return (ushort)(u >> 16);
}
__device__ inline ushort f2bfr(float f) {  // fast round (P only)
  union { float f; unsigned u; } cv; cv.f = f;
  return (ushort)((cv.u + 0x8000u) >> 16);
}
__device__ inline float bf2f(ushort u) {
  union { unsigned u; float f; } cv; cv.u = ((unsigned)u) << 16; return cv.f;
}

__device__ inline void async_load16(const void* g, void* l) {
  __builtin_amdgcn_global_load_lds(
      (const __attribute__((address_space(1))) void*)g,
      (__attribute__((address_space(3))) void*)l, 16, 0, 0);
}

__device__ __forceinline__ bf16x8 ones_frag() {
  bf16x8 v;
#pragma unroll
  for (int i = 0; i < 8; i++) v[i] = (short)0x3F80;  // bf16 1.0
  return v;
}

// ---------------------------------------------------------------------------
// fp32 -> bf16 conversion, 4 elems/thread
// ---------------------------------------------------------------------------
__global__ __launch_bounds__(256) void f32_to_bf16(
    const float* __restrict__ in, ushort* __restrict__ outp) {
  int i = (blockIdx.x * 256 + threadIdx.x) * 4;
  float4 v = *(const float4*)(in + i);
  ushort4 o;
  o.x = f2bf(v.x); o.y = f2bf(v.y); o.z = f2bf(v.z); o.w = f2bf(v.w);
  *(ushort4*)(outp + i) = o;
}

// ---------------------------------------------------------------------------
// MFMA GEMM: out = A @ Wt^T + bias. bf16 in; out fp32 or bf16.
// 128x128 tile, BK=64 (16 iters at K=1024), m97 staging via global_load_lds.
// ---------------------------------------------------------------------------
#define GT 128
#define GBK 64
template <bool BF16OUT>
__global__ __launch_bounds__(256) void gemm_mfma_bt(
    const ushort* __restrict__ A, const ushort* __restrict__ Wt,
    const float* __restrict__ b0, const float* __restrict__ b1,
    const float* __restrict__ b2, void* __restrict__ outp,
    int N, int K) {
  __shared__ ushort As[GT * GBK] __attribute__((aligned(16)));
  __shared__ ushort Bs[GT * GBK] __attribute__((aligned(16)));
  int tid = threadIdx.x;
  int lane = tid & 63;
  int lrow = lane & 15, quad = lane >> 4;
  int wave = tid >> 6;
  int wr = wave >> 1, wc = wave & 1;
  int row0 = blockIdx.y * GT;
  int col0 = blockIdx.x * GT;
  const float* bias = (col0 < 1024) ? b0 : (col0 < 2048) ? b1 : b2;

  size_t ga[4], gb[4];
#pragma unroll
  for (int i = 0; i < 4; i++) {
    int cc = tid + i * 256;            // 1024 chunks of 16B per 128x64 tile
    int r = cc >> 3, col = (cc & 7) * 8;
    ga[i] = (size_t)(row0 + r) * K + col;
    gb[i] = (size_t)(col0 + r) * K + col;
  }

  f32x4 acc[4][4];
#pragma unroll
  for (int i = 0; i < 4; i++)
#pragma unroll
    for (int j = 0; j < 4; j++) acc[i][j] = (f32x4){0.f, 0.f, 0.f, 0.f};

  for (int k0 = 0; k0 < K; k0 += GBK) {
#pragma unroll
    for (int i = 0; i < 4; i++) {
      int cc = tid + i * 256;
      async_load16(A + ga[i] + k0, &As[cc * 8]);
      async_load16(Wt + gb[i] + k0, &Bs[cc * 8]);
    }
    __syncthreads();
#pragma unroll
    for (int kh = 0; kh < 2; kh++) {
      bf16x8 af[4], bfr[4];
#pragma unroll
      for (int i = 0; i < 4; i++)
        af[i] = *(const bf16x8*)&As[(wr * 64 + i * 16 + lrow) * GBK + kh * 32 + quad * 8];
#pragma unroll
      for (int j = 0; j < 4; j++)
        bfr[j] = *(const bf16x8*)&Bs[(wc * 64 + j * 16 + lrow) * GBK + kh * 32 + quad * 8];
#pragma unroll
      for (int i = 0; i < 4; i++)
#pragma unroll
        for (int j = 0; j < 4; j++)
          acc[i][j] = __builtin_amdgcn_mfma_f32_16x16x32_bf16(af[i], bfr[j], acc[i][j], 0, 0, 0);
    }
    __syncthreads();
  }

#pragma unroll
  for (int i = 0; i < 4; i++)
#pragma unroll
    for (int j = 0; j < 4; j++) {
      int n = col0 + wc * 64 + j * 16 + lrow;
      float bn = bias[n & 1023];
#pragma unroll
      for (int r = 0; r < 4; r++) {
        int m = row0 + wr * 64 + i * 16 + quad * 4 + r;
        float v = acc[i][j][r] + bn;
        if (BF16OUT) ((ushort*)outp)[(size_t)m * N + n] = f2bf(v);
        else         ((float*)outp)[(size_t)m * N + n] = v;
      }
    }
}

// ---------------------------------------------------------------------------
// RoPE + transpose (B,T,3C) bf16 (ptr pre-offset) -> (B,H,T,D) bf16.
// Q gets scale = 0.125 * log2(e) (attention works in exp2 domain).
// ---------------------------------------------------------------------------
__global__ __launch_bounds__(256) void rope_transpose_bf16(
    const ushort* __restrict__ in, ushort* __restrict__ outp, float scale) {
  int idx = blockIdx.x * blockDim.x + threadIdx.x;
  int i = idx & 31;
  int t = (idx >> 5) & (T - 1);
  int h = (idx >> 16) & (H - 1);
  int b = idx >> 20;
  const ushort* src = in + ((size_t)b * T + t) * (3 * C) + h * D;
  float xr = bf2f(src[i]);
  float xi = bf2f(src[i + 32]);
  // 10000^(-i/32) = exp2(-i * log2(10000)/32)
  float alpha = __builtin_amdgcn_exp2f((float)i * -0.415241011861f);
  float ang = (float)t * alpha;
  float c, s;
  __sincosf(ang, &s, &c);
  ushort* dst = outp + (((size_t)b * H + h) * T + t) * D;
  dst[i]      = f2bf((xr * c - xi * s) * scale);
  dst[i + 32] = f2bf((xr * s + xi * c) * scale);
}

// ---------------------------------------------------------------------------
// V transpose: (B,T,3C) bf16 (ptr pre-offset to V) -> (B,H,D,T) bf16
// ---------------------------------------------------------------------------
__global__ __launch_bounds__(256) void transpose_vt(
    const ushort* __restrict__ in, ushort* __restrict__ outp) {
  __shared__ ushort tile[64][65];
  int bh = blockIdx.y;
  int b = bh >> 4, h = bh & 15;
  int t0 = blockIdx.x * 64;
#pragma unroll
  for (int i = 0; i < 16; i++) {
    int lin = threadIdx.x + i * 256;
    int d = lin & 63, tq = lin >> 6;
    tile[d][tq] = in[((size_t)b * T + t0 + tq) * (3 * C) + h * D + d];
  }
  __syncthreads();
#pragma unroll
  for (int i = 0; i < 16; i++) {
    int lin = threadIdx.x + i * 256;
    int tq = lin & 63, d = lin >> 6;
    outp[((size_t)bh * D + d) * T + t0 + tq] = tile[d][tq];
  }
}

// ---------------------------------------------------------------------------
// MFMA flash attention v4: 128-query blocks (4 waves x 32q in 2 groups of 16),
// 64-key LDS tiles (double-buffered), no-max softmax in exp2 domain,
// l via ones-MFMA, P chunk-major in LDS (conflict-free b128 reads).
// MODE: 0 = both groups unmasked; 1 = g0 masked, g1 full; 2 = g1 masked, g0 skipped.
// ---------------------------------------------------------------------------
__device__ __forceinline__ void stage_kv(
    const ushort* kbh, const ushort* vbh, int s0,
    ushort* Kl, ushort* Vl, int tid) {
#pragma unroll
  for (int i = 0; i < 2; i++) {
    int c = tid + i * 256;              // 0..511 chunk of 64x64 tile
    int r = c >> 3, cc = c & 7;
    int g = (cc ^ (r & 7)) * 8;         // XOR-swizzled source col-chunk
    async_load16(kbh + (size_t)(s0 + r) * D + g, Kl + c * 8);
    async_load16(vbh + (size_t)r * T + s0 + g, Vl + c * 8);
  }
}

template <int MODE>
__device__ __forceinline__ void attn_step4(
    int s0, const ushort* KL, const ushort* VL, ushort* P,
    const bf16x8 (&qf)[2][2], int lrow, int quad, int sw0, int sw1,
    int qg0, int qg1, f32x4 (&o)[4][2], f32x4 (&ol)[2]) {
  bf16x8 kf0[4], kf1[4];
#pragma unroll
  for (int kt = 0; kt < 4; kt++) {
    int base = (kt * 16 + lrow) * 64;
    kf0[kt] = *(const bf16x8*)&KL[base + sw0];
    kf1[kt] = *(const bf16x8*)&KL[base + sw1];
  }
  bf16x8 vf0[4], vf1[4];
#pragma unroll
  for (int ds = 0; ds < 4; ds++) {
    int base = (ds * 16 + lrow) * 64;
    vf0[ds] = *(const bf16x8*)&VL[base + sw0];
    vf1[ds] = *(const bf16x8*)&VL[base + sw1];
  }
#pragma unroll
  for (int g = 0; g < 2; g++) {
    if (MODE == 2 && g == 0) continue;
    int qg = g ? qg1 : qg0;
    f32x4 st[4];
#pragma unroll
    for (int kt = 0; kt < 4; kt++) {
      f32x4 z = {0.f, 0.f, 0.f, 0.f};
      st[kt] = __builtin_amdgcn_mfma_f32_16x16x32_bf16(kf0[kt], qf[g][0], z, 0, 0, 0);
      st[kt] = __builtin_amdgcn_mfma_f32_16x16x32_bf16(kf1[kt], qf[g][1], st[kt], 0, 0, 0);
    }
    if ((MODE == 1 && g == 0) || (MODE == 2 && g == 1)) {
#pragma unroll
      for (int kt = 0; kt < 4; kt++)
#pragma unroll
        for (int r = 0; r < 4; r++)
          if (s0 + kt * 16 + quad * 4 + r > qg) st[kt][r] = -1e30f;
    }
    // P = exp2(st) (scale*log2e folded into Q); pack chunk-major:
    // P[chunk c][q32][8 elems]; this lane's 4 keys = chunk 2kt+(quad>>1), half quad&1
#pragma unroll
    for (int kt = 0; kt < 4; kt++) {
      ushort4 pk;
      pk.x = f2bfr(__builtin_amdgcn_exp2f(st[kt][0]));
      pk.y = f2bfr(__builtin_amdgcn_exp2f(st[kt][1]));
      pk.z = f2bfr(__builtin_amdgcn_exp2f(st[kt][2]));
      pk.w = f2bfr(__builtin_amdgcn_exp2f(st[kt][3]));
      *(ushort4*)&P[((2 * kt + (quad >> 1)) * 32 + g * 16 + lrow) * 8 + (quad & 1) * 4] = pk;
    }
  }
  asm volatile("" ::: "memory");   // keep ds_read after ds_write (in-wave order)
  bf16x8 ones = ones_frag();
#pragma unroll
  for (int g = 0; g < 2; g++) {
    if (MODE == 2 && g == 0) continue;
    // reads are lane-contiguous: addr = lane*16 (+g*256, +1024 for pf1)
    bf16x8 pf0 = *(const bf16x8*)&P[(quad * 32 + g * 16 + lrow) * 8];
    bf16x8 pf1 = *(const bf16x8*)&P[((quad + 4) * 32 + g * 16 + lrow) * 8];
    ol[g] = __builtin_amdgcn_mfma_f32_16x16x32_bf16(ones, pf0, ol[g], 0, 0, 0);
    ol[g] = __builtin_amdgcn_mfma_f32_16x16x32_bf16(ones, pf1, ol[g], 0, 0, 0);
#pragma unroll
    for (int ds = 0; ds < 4; ds++) {
      o[ds][g] = __builtin_amdgcn_mfma_f32_16x16x32_bf16(vf0[ds], pf0, o[ds][g], 0, 0, 0);
      o[ds][g] = __builtin_amdgcn_mfma_f32_16x16x32_bf16(vf1[ds], pf1, o[ds][g], 0, 0, 0);
    }
  }
}

__global__ __launch_bounds__(256, 3) void attn_mfma4(
    const ushort* __restrict__ qb_, const ushort* __restrict__ kb_,
    const ushort* __restrict__ vtb_, ushort* __restrict__ y) {
  __shared__ ushort Kl[2][64 * 64] __attribute__((aligned(16)));
  __shared__ ushort Vl[2][64 * 64] __attribute__((aligned(16)));
  __shared__ ushort Pl[4][2048] __attribute__((aligned(16)));
  int tid = threadIdx.x;
  int wave = tid >> 6, lane = tid & 63;
  int lrow = lane & 15, quad = lane >> 4;
  int qbi = 15 - (int)(blockIdx.x >> 6);   // descending: longest first
  int bh = blockIdx.x & 63;
  int b = bh >> 4, h = bh & 15;
  int Q0 = qbi * 128;
  ushort* P = Pl[wave];
  const ushort* kbh = kb_ + (size_t)bh * T * D;
  const ushort* vbh = vtb_ + (size_t)bh * D * T;

  int qg0 = Q0 + wave * 16 + lrow;         // group 0 query of this lane
  int qg1 = qg0 + 64;                      // group 1 query
  bf16x8 qf[2][2];
  {
    const ushort* qp0 = qb_ + ((size_t)bh * T + qg0) * D + quad * 8;
    qf[0][0] = *(const bf16x8*)qp0;
    qf[0][1] = *(const bf16x8*)(qp0 + 32);
    const ushort* qp1 = qb_ + ((size_t)bh * T + qg1) * D + quad * 8;
    qf[1][0] = *(const bf16x8*)qp1;
    qf[1][1] = *(const bf16x8*)(qp1 + 32);
  }
  int r7 = lrow & 7;
  int sw0 = (quad ^ r7) * 8;
  int sw1 = ((quad + 4) ^ r7) * 8;

  f32x4 o[4][2];
#pragma unroll
  for (int ds = 0; ds < 4; ds++)
#pragma unroll
    for (int g = 0; g < 2; g++) o[ds][g] = (f32x4){0.f, 0.f, 0.f, 0.f};
  f32x4 ol[2] = {(f32x4){0.f, 0.f, 0.f, 0.f}, (f32x4){0.f, 0.f, 0.f, 0.f}};

  int trips = 2 * qbi + 2;
  stage_kv(kbh, vbh, 0, Kl[0], Vl[0], tid);
  int it = 0;
  for (; it < trips - 2; ++it) {
    __syncthreads();
    stage_kv(kbh, vbh, (it + 1) * 64, Kl[(it + 1) & 1], Vl[(it + 1) & 1], tid);
    attn_step4<0>(it * 64, Kl[it & 1], Vl[it & 1], P, qf, lrow, quad, sw0, sw1,
                  qg0, qg1, o, ol);
  }
  __syncthreads();
  stage_kv(kbh, vbh, (it + 1) * 64, Kl[(it + 1) & 1], Vl[(it + 1) & 1], tid);
  attn_step4<1>(it * 64, Kl[it & 1], Vl[it & 1], P, qf, lrow, quad, sw0, sw1,
                qg0, qg1, o, ol);
  ++it;
  __syncthreads();
  attn_step4<2>(it * 64, Kl[it & 1], Vl[it & 1], P, qf, lrow, quad, sw0, sw1,
                qg0, qg1, o, ol);

  // epilogue: normalize by l (= ones-MFMA row sums), store bf16 (B,T,C)
#pragma unroll
  for (int g = 0; g < 2; g++) {
    float inv = 1.f / ol[g][0];
    int qg = g ? qg1 : qg0;
#pragma unroll
    for (int ds = 0; ds < 4; ds++) {
      ushort4 pk;
      pk.x = f2bf(o[ds][g][0] * inv);
      pk.y = f2bf(o[ds][g][1] * inv);
      pk.z = f2bf(o[ds][g][2] * inv);
      pk.w = f2bf(o[ds][g][3] * inv);
      *(ushort4*)(y + ((size_t)b * T + qg) * C + h * D + ds * 16 + quad * 4) = pk;
    }
  }
}

// ---------------------------------------------------------------------------
extern "C" void kernel_launch(void* const* d_in, const int* in_sizes, int n_in,
                              void* d_out, int out_size, void* d_ws, size_t ws_size,
                              hipStream_t stream) {
  const float* x  = (const float*)d_in[0];
  const float* wq = (const float*)d_in[1];
  const float* bq = (const float*)d_in[2];
  const float* wk = (const float*)d_in[3];
  const float* bk = (const float*)d_in[4];
  const float* wv = (const float*)d_in[5];
  const float* bv = (const float*)d_in[6];
  const float* wp = (const float*)d_in[7];
  const float* bp = (const float*)d_in[8];
  float* out = (float*)d_out;

  ushort* xb    = (ushort*)d_ws;            // (B,T,C)   bf16
  ushort* qkvb  = xb + BTC;                 // (B,T,3C)  bf16 (y aliases later)
  ushort* qb    = qkvb + 3 * BTC;           // (B,H,T,D) bf16 (scale 0.125*log2e)
  ushort* kb    = qb + BTC;
  ushort* vtb   = kb + BTC;                 // (B,H,D,T) bf16
  ushort* wqkvb = vtb + BTC;                // (3C,C) bf16
  ushort* wpb   = wqkvb + (size_t)3 * C * C;

  f32_to_bf16<<<(int)(BTC / 1024), 256, 0, stream>>>(x, xb);
  f32_to_bf16<<<(C * C) / 1024, 256, 0, stream>>>(wq, wqkvb);
  f32_to_bf16<<<(C * C) / 1024, 256, 0, stream>>>(wk, wqkvb + (size_t)C * C);
  f32_to_bf16<<<(C * C) / 1024, 256, 0, stream>>>(wv, wqkvb + (size_t)2 * C * C);
  f32_to_bf16<<<(C * C) / 1024, 256, 0, stream>>>(wp, wpb);

  dim3 qkv_grid(3 * C / GT, M / GT);        // (24, 64)
  gemm_mfma_bt<true><<<qkv_grid, 256, 0, stream>>>(
      xb, wqkvb, bq, bk, bv, qkvb, 3 * C, C);

  int rope_blocks = (B * H * T * 32) / 256;
  rope_transpose_bf16<<<rope_blocks, 256, 0, stream>>>(qkvb, qb, 0.18033688011112042f);
  rope_transpose_bf16<<<rope_blocks, 256, 0, stream>>>(qkvb + C, kb, 1.0f);
  dim3 vt_grid(T / 64, B * H);
  transpose_vt<<<vt_grid, 256, 0, stream>>>(qkvb + 2 * C, vtb);

  attn_mfma4<<<(B * H * T / 128), 256, 0, stream>>>(qb, kb, vtb, qkvb);

  dim3 proj_grid(C / GT, M / GT);           // (8, 64)
  gemm_mfma_bt<false><<<proj_grid, 256, 0, stream>>>(
      qkvb, wpb, bp, bp, bp, out, C, C);
}

// Round 7
// 263.558 us; speedup vs baseline: 39.9930x; 1.1011x over previous
//
#include <hip/hip_runtime.h>
#include <math.h>

constexpr int B = 4, T = 2048, C = 1024, H = 16, D = 64;
constexpr int M = B * T;
constexpr size_t BTC = (size_t)B * T * C;

typedef short bf16x8 __attribute__((ext_vector_type(8)));
typedef float f32x4 __attribute__((ext_vector_type(4)));

__device__ inline ushort f2bf(float f) {
  union { float f; unsigned u; } cv; cv.f = f;
  unsigned u = cv.u;
  u += 0x7fffu + ((u >> 16) & 1u);   // round-to-nearest-even
  return (ushort)(u >> 16);
}
__device__ inline ushort f2bfr(float f) {  // fast round (P only)
  union { float f; unsigned u; } cv; cv.f = f;
  return (ushort)((cv.u + 0x8000u) >> 16);
}
__device__ inline float bf2f(ushort u) {
  union { unsigned u; float f; } cv; cv.u = ((unsigned)u) << 16; return cv.f;
}

__device__ inline void async_load16(const void* g, void* l) {
  __builtin_amdgcn_global_load_lds(
      (const __attribute__((address_space(1))) void*)g,
      (__attribute__((address_space(3))) void*)l, 16, 0, 0);
}

__device__ __forceinline__ bf16x8 ones_frag() {
  bf16x8 v;
#pragma unroll
  for (int i = 0; i < 8; i++) v[i] = (short)0x3F80;  // bf16 1.0
  return v;
}

// ---------------------------------------------------------------------------
// fp32 -> bf16 conversion, 4 elems/thread
// ---------------------------------------------------------------------------
__global__ __launch_bounds__(256) void f32_to_bf16(
    const float* __restrict__ in, ushort* __restrict__ outp) {
  int i = (blockIdx.x * 256 + threadIdx.x) * 4;
  float4 v = *(const float4*)(in + i);
  ushort4 o;
  o.x = f2bf(v.x); o.y = f2bf(v.y); o.z = f2bf(v.z); o.w = f2bf(v.w);
  *(ushort4*)(outp + i) = o;
}

// Convert 4 weight matrices (C*C each) into contiguous dst in one launch.
__global__ __launch_bounds__(256) void conv_weights(
    const float* __restrict__ w0, const float* __restrict__ w1,
    const float* __restrict__ w2, const float* __restrict__ w3,
    ushort* __restrict__ outp) {
  const int seg_blocks = (C * C) / 1024;   // 1024 blocks per matrix
  int seg = blockIdx.x / seg_blocks;
  int blk = blockIdx.x - seg * seg_blocks;
  const float* src = (seg == 0) ? w0 : (seg == 1) ? w1 : (seg == 2) ? w2 : w3;
  int i = (blk * 256 + threadIdx.x) * 4;
  float4 v = *(const float4*)(src + i);
  ushort4 o;
  o.x = f2bf(v.x); o.y = f2bf(v.y); o.z = f2bf(v.z); o.w = f2bf(v.w);
  *(ushort4*)(outp + (size_t)seg * C * C + i) = o;
}

// ---------------------------------------------------------------------------
// MFMA GEMM: out = A @ Wt^T + bias. bf16 in; out fp32 or bf16.
// 128x128 tile, BK=64, global_load_lds staging, XOR-swizzled LDS chunks
// (row stride = 128 B = bank period; swizzle spreads each 16-lane phase
// across all 8 16-B slots -> 2-way = free).
// ---------------------------------------------------------------------------
#define GT 128
#define GBK 64
template <bool BF16OUT>
__global__ __launch_bounds__(256) void gemm_mfma_bt(
    const ushort* __restrict__ A, const ushort* __restrict__ Wt,
    const float* __restrict__ b0, const float* __restrict__ b1,
    const float* __restrict__ b2, void* __restrict__ outp,
    int N, int K) {
  __shared__ ushort As[GT * GBK] __attribute__((aligned(16)));
  __shared__ ushort Bs[GT * GBK] __attribute__((aligned(16)));
  int tid = threadIdx.x;
  int lane = tid & 63;
  int lrow = lane & 15, quad = lane >> 4;
  int wave = tid >> 6;
  int wr = wave >> 1, wc = wave & 1;
  int row0 = blockIdx.y * GT;
  int col0 = blockIdx.x * GT;
  const float* bias = (col0 < 1024) ? b0 : (col0 < 2048) ? b1 : b2;

  size_t ga[4], gb[4];
#pragma unroll
  for (int i = 0; i < 4; i++) {
    int cc = tid + i * 256;            // 1024 chunks of 16B per 128x64 tile
    int r = cc >> 3, cl = cc & 7;
    int g = (cl ^ (r & 7)) * 8;        // XOR-swizzled source col-chunk
    ga[i] = (size_t)(row0 + r) * K + g;
    gb[i] = (size_t)(col0 + r) * K + g;
  }
  int x7 = lrow & 7;

  f32x4 acc[4][4];
#pragma unroll
  for (int i = 0; i < 4; i++)
#pragma unroll
    for (int j = 0; j < 4; j++) acc[i][j] = (f32x4){0.f, 0.f, 0.f, 0.f};

  for (int k0 = 0; k0 < K; k0 += GBK) {
#pragma unroll
    for (int i = 0; i < 4; i++) {
      int cc = tid + i * 256;
      async_load16(A + ga[i] + k0, &As[cc * 8]);
      async_load16(Wt + gb[i] + k0, &Bs[cc * 8]);
    }
    __syncthreads();
#pragma unroll
    for (int kh = 0; kh < 2; kh++) {
      int slot = ((kh * 4 + quad) ^ x7) * 8;   // swizzled k-chunk offset
      bf16x8 af[4], bfr[4];
#pragma unroll
      for (int i = 0; i < 4; i++)
        af[i] = *(const bf16x8*)&As[(wr * 64 + i * 16 + lrow) * GBK + slot];
#pragma unroll
      for (int j = 0; j < 4; j++)
        bfr[j] = *(const bf16x8*)&Bs[(wc * 64 + j * 16 + lrow) * GBK + slot];
#pragma unroll
      for (int i = 0; i < 4; i++)
#pragma unroll
        for (int j = 0; j < 4; j++)
          acc[i][j] = __builtin_amdgcn_mfma_f32_16x16x32_bf16(af[i], bfr[j], acc[i][j], 0, 0, 0);
    }
    __syncthreads();
  }

#pragma unroll
  for (int i = 0; i < 4; i++)
#pragma unroll
    for (int j = 0; j < 4; j++) {
      int n = col0 + wc * 64 + j * 16 + lrow;
      float bn = bias[n & 1023];
#pragma unroll
      for (int r = 0; r < 4; r++) {
        int m = row0 + wr * 64 + i * 16 + quad * 4 + r;
        float v = acc[i][j][r] + bn;
        if (BF16OUT) ((ushort*)outp)[(size_t)m * N + n] = f2bf(v);
        else         ((float*)outp)[(size_t)m * N + n] = v;
      }
    }
}

// ---------------------------------------------------------------------------
// RoPE + transpose for Q AND K in one launch (blockIdx.y: 0=Q, 1=K).
// (B,T,3C) bf16 -> (B,H,T,D) bf16. Q scaled by 0.125*log2e (exp2 domain).
// ---------------------------------------------------------------------------
__global__ __launch_bounds__(256) void rope_transpose_qk(
    const ushort* __restrict__ qkv, ushort* __restrict__ qout,
    ushort* __restrict__ kout) {
  int idx = blockIdx.x * blockDim.x + threadIdx.x;
  int i = idx & 31;
  int t = (idx >> 5) & (T - 1);
  int h = (idx >> 16) & (H - 1);
  int b = idx >> 20;
  int isK = blockIdx.y;
  const ushort* src = qkv + ((size_t)b * T + t) * (3 * C) + isK * C + h * D;
  float scale = isK ? 1.0f : 0.18033688011112042f;  // 0.125*log2(e)
  float xr = bf2f(src[i]);
  float xi = bf2f(src[i + 32]);
  float alpha = __builtin_amdgcn_exp2f((float)i * -0.415241011861f);
  float ang = (float)t * alpha;
  float c, s;
  __sincosf(ang, &s, &c);
  ushort* dst = (isK ? kout : qout) + (((size_t)b * H + h) * T + t) * D;
  dst[i]      = f2bf((xr * c - xi * s) * scale);
  dst[i + 32] = f2bf((xr * s + xi * c) * scale);
}

// ---------------------------------------------------------------------------
// V transpose: (B,T,3C) bf16 (ptr pre-offset to V) -> (B,H,D,T) bf16
// ---------------------------------------------------------------------------
__global__ __launch_bounds__(256) void transpose_vt(
    const ushort* __restrict__ in, ushort* __restrict__ outp) {
  __shared__ ushort tile[64][65];
  int bh = blockIdx.y;
  int b = bh >> 4, h = bh & 15;
  int t0 = blockIdx.x * 64;
#pragma unroll
  for (int i = 0; i < 16; i++) {
    int lin = threadIdx.x + i * 256;
    int d = lin & 63, tq = lin >> 6;
    tile[d][tq] = in[((size_t)b * T + t0 + tq) * (3 * C) + h * D + d];
  }
  __syncthreads();
#pragma unroll
  for (int i = 0; i < 16; i++) {
    int lin = threadIdx.x + i * 256;
    int tq = lin & 63, d = lin >> 6;
    outp[((size_t)bh * D + d) * T + t0 + tq] = tile[d][tq];
  }
}

// ---------------------------------------------------------------------------
// MFMA flash attention v4 (unchanged from round 6).
// ---------------------------------------------------------------------------
__device__ __forceinline__ void stage_kv(
    const ushort* kbh, const ushort* vbh, int s0,
    ushort* Kl, ushort* Vl, int tid) {
#pragma unroll
  for (int i = 0; i < 2; i++) {
    int c = tid + i * 256;
    int r = c >> 3, cc = c & 7;
    int g = (cc ^ (r & 7)) * 8;
    async_load16(kbh + (size_t)(s0 + r) * D + g, Kl + c * 8);
    async_load16(vbh + (size_t)r * T + s0 + g, Vl + c * 8);
  }
}

template <int MODE>
__device__ __forceinline__ void attn_step4(
    int s0, const ushort* KL, const ushort* VL, ushort* P,
    const bf16x8 (&qf)[2][2], int lrow, int quad, int sw0, int sw1,
    int qg0, int qg1, f32x4 (&o)[4][2], f32x4 (&ol)[2]) {
  bf16x8 kf0[4], kf1[4];
#pragma unroll
  for (int kt = 0; kt < 4; kt++) {
    int base = (kt * 16 + lrow) * 64;
    kf0[kt] = *(const bf16x8*)&KL[base + sw0];
    kf1[kt] = *(const bf16x8*)&KL[base + sw1];
  }
  bf16x8 vf0[4], vf1[4];
#pragma unroll
  for (int ds = 0; ds < 4; ds++) {
    int base = (ds * 16 + lrow) * 64;
    vf0[ds] = *(const bf16x8*)&VL[base + sw0];
    vf1[ds] = *(const bf16x8*)&VL[base + sw1];
  }
#pragma unroll
  for (int g = 0; g < 2; g++) {
    if (MODE == 2 && g == 0) continue;
    int qg = g ? qg1 : qg0;
    f32x4 st[4];
#pragma unroll
    for (int kt = 0; kt < 4; kt++) {
      f32x4 z = {0.f, 0.f, 0.f, 0.f};
      st[kt] = __builtin_amdgcn_mfma_f32_16x16x32_bf16(kf0[kt], qf[g][0], z, 0, 0, 0);
      st[kt] = __builtin_amdgcn_mfma_f32_16x16x32_bf16(kf1[kt], qf[g][1], st[kt], 0, 0, 0);
    }
    if ((MODE == 1 && g == 0) || (MODE == 2 && g == 1)) {
#pragma unroll
      for (int kt = 0; kt < 4; kt++)
#pragma unroll
        for (int r = 0; r < 4; r++)
          if (s0 + kt * 16 + quad * 4 + r > qg) st[kt][r] = -1e30f;
    }
#pragma unroll
    for (int kt = 0; kt < 4; kt++) {
      ushort4 pk;
      pk.x = f2bfr(__builtin_amdgcn_exp2f(st[kt][0]));
      pk.y = f2bfr(__builtin_amdgcn_exp2f(st[kt][1]));
      pk.z = f2bfr(__builtin_amdgcn_exp2f(st[kt][2]));
      pk.w = f2bfr(__builtin_amdgcn_exp2f(st[kt][3]));
      *(ushort4*)&P[((2 * kt + (quad >> 1)) * 32 + g * 16 + lrow) * 8 + (quad & 1) * 4] = pk;
    }
  }
  asm volatile("" ::: "memory");
  bf16x8 ones = ones_frag();
#pragma unroll
  for (int g = 0; g < 2; g++) {
    if (MODE == 2 && g == 0) continue;
    bf16x8 pf0 = *(const bf16x8*)&P[(quad * 32 + g * 16 + lrow) * 8];
    bf16x8 pf1 = *(const bf16x8*)&P[((quad + 4) * 32 + g * 16 + lrow) * 8];
    ol[g] = __builtin_amdgcn_mfma_f32_16x16x32_bf16(ones, pf0, ol[g], 0, 0, 0);
    ol[g] = __builtin_amdgcn_mfma_f32_16x16x32_bf16(ones, pf1, ol[g], 0, 0, 0);
#pragma unroll
    for (int ds = 0; ds < 4; ds++) {
      o[ds][g] = __builtin_amdgcn_mfma_f32_16x16x32_bf16(vf0[ds], pf0, o[ds][g], 0, 0, 0);
      o[ds][g] = __builtin_amdgcn_mfma_f32_16x16x32_bf16(vf1[ds], pf1, o[ds][g], 0, 0, 0);
    }
  }
}

__global__ __launch_bounds__(256, 3) void attn_mfma4(
    const ushort* __restrict__ qb_, const ushort* __restrict__ kb_,
    const ushort* __restrict__ vtb_, ushort* __restrict__ y) {
  __shared__ ushort Kl[2][64 * 64] __attribute__((aligned(16)));
  __shared__ ushort Vl[2][64 * 64] __attribute__((aligned(16)));
  __shared__ ushort Pl[4][2048] __attribute__((aligned(16)));
  int tid = threadIdx.x;
  int wave = tid >> 6, lane = tid & 63;
  int lrow = lane & 15, quad = lane >> 4;
  int qbi = 15 - (int)(blockIdx.x >> 6);
  int bh = blockIdx.x & 63;
  int b = bh >> 4, h = bh & 15;
  int Q0 = qbi * 128;
  ushort* P = Pl[wave];
  const ushort* kbh = kb_ + (size_t)bh * T * D;
  const ushort* vbh = vtb_ + (size_t)bh * D * T;

  int qg0 = Q0 + wave * 16 + lrow;
  int qg1 = qg0 + 64;
  bf16x8 qf[2][2];
  {
    const ushort* qp0 = qb_ + ((size_t)bh * T + qg0) * D + quad * 8;
    qf[0][0] = *(const bf16x8*)qp0;
    qf[0][1] = *(const bf16x8*)(qp0 + 32);
    const ushort* qp1 = qb_ + ((size_t)bh * T + qg1) * D + quad * 8;
    qf[1][0] = *(const bf16x8*)qp1;
    qf[1][1] = *(const bf16x8*)(qp1 + 32);
  }
  int r7 = lrow & 7;
  int sw0 = (quad ^ r7) * 8;
  int sw1 = ((quad + 4) ^ r7) * 8;

  f32x4 o[4][2];
#pragma unroll
  for (int ds = 0; ds < 4; ds++)
#pragma unroll
    for (int g = 0; g < 2; g++) o[ds][g] = (f32x4){0.f, 0.f, 0.f, 0.f};
  f32x4 ol[2] = {(f32x4){0.f, 0.f, 0.f, 0.f}, (f32x4){0.f, 0.f, 0.f, 0.f}};

  int trips = 2 * qbi + 2;
  stage_kv(kbh, vbh, 0, Kl[0], Vl[0], tid);
  int it = 0;
  for (; it < trips - 2; ++it) {
    __syncthreads();
    stage_kv(kbh, vbh, (it + 1) * 64, Kl[(it + 1) & 1], Vl[(it + 1) & 1], tid);
    attn_step4<0>(it * 64, Kl[it & 1], Vl[it & 1], P, qf, lrow, quad, sw0, sw1,
                  qg0, qg1, o, ol);
  }
  __syncthreads();
  stage_kv(kbh, vbh, (it + 1) * 64, Kl[(it + 1) & 1], Vl[(it + 1) & 1], tid);
  attn_step4<1>(it * 64, Kl[it & 1], Vl[it & 1], P, qf, lrow, quad, sw0, sw1,
                qg0, qg1, o, ol);
  ++it;
  __syncthreads();
  attn_step4<2>(it * 64, Kl[it & 1], Vl[it & 1], P, qf, lrow, quad, sw0, sw1,
                qg0, qg1, o, ol);

#pragma unroll
  for (int g = 0; g < 2; g++) {
    float inv = 1.f / ol[g][0];
    int qg = g ? qg1 : qg0;
#pragma unroll
    for (int ds = 0; ds < 4; ds++) {
      ushort4 pk;
      pk.x = f2bf(o[ds][g][0] * inv);
      pk.y = f2bf(o[ds][g][1] * inv);
      pk.z = f2bf(o[ds][g][2] * inv);
      pk.w = f2bf(o[ds][g][3] * inv);
      *(ushort4*)(y + ((size_t)b * T + qg) * C + h * D + ds * 16 + quad * 4) = pk;
    }
  }
}

// ---------------------------------------------------------------------------
extern "C" void kernel_launch(void* const* d_in, const int* in_sizes, int n_in,
                              void* d_out, int out_size, void* d_ws, size_t ws_size,
                              hipStream_t stream) {
  const float* x  = (const float*)d_in[0];
  const float* wq = (const float*)d_in[1];
  const float* bq = (const float*)d_in[2];
  const float* wk = (const float*)d_in[3];
  const float* bk = (const float*)d_in[4];
  const float* wv = (const float*)d_in[5];
  const float* bv = (const float*)d_in[6];
  const float* wp = (const float*)d_in[7];
  const float* bp = (const float*)d_in[8];
  float* out = (float*)d_out;

  ushort* xb    = (ushort*)d_ws;            // (B,T,C)   bf16
  ushort* qkvb  = xb + BTC;                 // (B,T,3C)  bf16 (y aliases later)
  ushort* qb    = qkvb + 3 * BTC;           // (B,H,T,D) bf16 (scale 0.125*log2e)
  ushort* kb    = qb + BTC;
  ushort* vtb   = kb + BTC;                 // (B,H,D,T) bf16
  ushort* wqkvb = vtb + BTC;                // (3C,C) bf16, wpb contiguous after
  ushort* wpb   = wqkvb + (size_t)3 * C * C;

  f32_to_bf16<<<(int)(BTC / 1024), 256, 0, stream>>>(x, xb);
  conv_weights<<<4 * (C * C) / 1024, 256, 0, stream>>>(wq, wk, wv, wp, wqkvb);

  dim3 qkv_grid(3 * C / GT, M / GT);        // (24, 64)
  gemm_mfma_bt<true><<<qkv_grid, 256, 0, stream>>>(
      xb, wqkvb, bq, bk, bv, qkvb, 3 * C, C);

  dim3 rope_grid((B * H * T * 32) / 256, 2);
  rope_transpose_qk<<<rope_grid, 256, 0, stream>>>(qkvb, qb, kb);
  dim3 vt_grid(T / 64, B * H);
  transpose_vt<<<vt_grid, 256, 0, stream>>>(qkvb + 2 * C, vtb);

  attn_mfma4<<<(B * H * T / 128), 256, 0, stream>>>(qb, kb, vtb, qkvb);

  dim3 proj_grid(C / GT, M / GT);           // (8, 64)
  gemm_mfma_bt<false><<<proj_grid, 256, 0, stream>>>(
      qkvb, wpb, bp, bp, bp, out, C, C);
}

// Round 8
// 246.846 us; speedup vs baseline: 42.7005x; 1.0677x over previous
//
#include <hip/hip_runtime.h>
#include <math.h>

constexpr int B = 4, T = 2048, C = 1024, H = 16, D = 64;
constexpr int M = B * T;
constexpr size_t BTC = (size_t)B * T * C;
constexpr float QSCALE = 0.18033688011112042f;   // 0.125 * log2(e)
constexpr float ROPE_C = -0.415241011861f;       // -log2(10000)/32

typedef short bf16x8 __attribute__((ext_vector_type(8)));
typedef float f32x4 __attribute__((ext_vector_type(4)));

__device__ inline ushort f2bf(float f) {
  union { float f; unsigned u; } cv; cv.f = f;
  unsigned u = cv.u;
  u += 0x7fffu + ((u >> 16) & 1u);   // round-to-nearest-even
  return (ushort)(u >> 16);
}
__device__ inline ushort f2bfr(float f) {  // fast round (P only)
  union { float f; unsigned u; } cv; cv.f = f;
  return (ushort)((cv.u + 0x8000u) >> 16);
}

__device__ inline void async_load16(const void* g, void* l) {
  __builtin_amdgcn_global_load_lds(
      (const __attribute__((address_space(1))) void*)g,
      (__attribute__((address_space(3))) void*)l, 16, 0, 0);
}

__device__ __forceinline__ bf16x8 ones_frag() {
  bf16x8 v;
#pragma unroll
  for (int i = 0; i < 8; i++) v[i] = (short)0x3F80;  // bf16 1.0
  return v;
}

// ---------------------------------------------------------------------------
// fp32 -> bf16 conversion, 4 elems/thread
// ---------------------------------------------------------------------------
__global__ __launch_bounds__(256) void f32_to_bf16(
    const float* __restrict__ in, ushort* __restrict__ outp) {
  int i = (blockIdx.x * 256 + threadIdx.x) * 4;
  float4 v = *(const float4*)(in + i);
  ushort4 o;
  o.x = f2bf(v.x); o.y = f2bf(v.y); o.z = f2bf(v.z); o.w = f2bf(v.w);
  *(ushort4*)(outp + i) = o;
}

// Convert 4 weight matrices (C*C each) into contiguous dst in one launch.
__global__ __launch_bounds__(256) void conv_weights(
    const float* __restrict__ w0, const float* __restrict__ w1,
    const float* __restrict__ w2, const float* __restrict__ w3,
    ushort* __restrict__ outp) {
  const int seg_blocks = (C * C) / 1024;
  int seg = blockIdx.x / seg_blocks;
  int blk = blockIdx.x - seg * seg_blocks;
  const float* src = (seg == 0) ? w0 : (seg == 1) ? w1 : (seg == 2) ? w2 : w3;
  int i = (blk * 256 + threadIdx.x) * 4;
  float4 v = *(const float4*)(src + i);
  ushort4 o;
  o.x = f2bf(v.x); o.y = f2bf(v.y); o.z = f2bf(v.z); o.w = f2bf(v.w);
  *(ushort4*)(outp + (size_t)seg * C * C + i) = o;
}

// ---------------------------------------------------------------------------
// MFMA GEMM: 128x128 tile, BK=64, global_load_lds staging, XOR-swizzled LDS.
// OM=0: plain fp32 out + bias (proj).
// OM=1: fused QKV epilogue — RoPE(Q,K) in-register (pairs (d,d+32) are
//       lane-local), Q scaled to exp2 domain, writes Q,K (B,H,T,D) and
//       V transposed (B,H,D,T). Replaces the rope/vt passes entirely.
// ---------------------------------------------------------------------------
#define GT 128
#define GBK 64
template <int OM>
__global__ __launch_bounds__(256) void gemm_mfma_bt(
    const ushort* __restrict__ A, const ushort* __restrict__ Wt,
    const float* __restrict__ b0, const float* __restrict__ b1,
    const float* __restrict__ b2, void* __restrict__ out1,
    void* __restrict__ out2, void* __restrict__ out3,
    int N, int K) {
  __shared__ ushort As[GT * GBK] __attribute__((aligned(16)));
  __shared__ ushort Bs[GT * GBK] __attribute__((aligned(16)));
  int tid = threadIdx.x;
  int lane = tid & 63;
  int lrow = lane & 15, quad = lane >> 4;
  int wave = tid >> 6;
  int wr = wave >> 1, wc = wave & 1;
  int row0 = blockIdx.y * GT;
  int col0 = blockIdx.x * GT;
  const float* bias = (col0 < 1024) ? b0 : (col0 < 2048) ? b1 : b2;

  size_t ga[4], gb[4];
#pragma unroll
  for (int i = 0; i < 4; i++) {
    int cc = tid + i * 256;
    int r = cc >> 3, cl = cc & 7;
    int g = (cl ^ (r & 7)) * 8;        // XOR-swizzled source col-chunk
    ga[i] = (size_t)(row0 + r) * K + g;
    gb[i] = (size_t)(col0 + r) * K + g;
  }
  int x7 = lrow & 7;

  f32x4 acc[4][4];
#pragma unroll
  for (int i = 0; i < 4; i++)
#pragma unroll
    for (int j = 0; j < 4; j++) acc[i][j] = (f32x4){0.f, 0.f, 0.f, 0.f};

  for (int k0 = 0; k0 < K; k0 += GBK) {
#pragma unroll
    for (int i = 0; i < 4; i++) {
      int cc = tid + i * 256;
      async_load16(A + ga[i] + k0, &As[cc * 8]);
      async_load16(Wt + gb[i] + k0, &Bs[cc * 8]);
    }
    __syncthreads();
#pragma unroll
    for (int kh = 0; kh < 2; kh++) {
      int slot = ((kh * 4 + quad) ^ x7) * 8;
      bf16x8 af[4], bfr[4];
#pragma unroll
      for (int i = 0; i < 4; i++)
        af[i] = *(const bf16x8*)&As[(wr * 64 + i * 16 + lrow) * GBK + slot];
#pragma unroll
      for (int j = 0; j < 4; j++)
        bfr[j] = *(const bf16x8*)&Bs[(wc * 64 + j * 16 + lrow) * GBK + slot];
#pragma unroll
      for (int i = 0; i < 4; i++)
#pragma unroll
        for (int j = 0; j < 4; j++)
          acc[i][j] = __builtin_amdgcn_mfma_f32_16x16x32_bf16(af[i], bfr[j], acc[i][j], 0, 0, 0);
    }
    __syncthreads();
  }

  int nb = col0 + wc * 64;             // head-aligned (64 | nb)
  int mbase = row0 + wr * 64;
  float bn[4];
#pragma unroll
  for (int j = 0; j < 4; j++) bn[j] = bias[(nb & 1023) + j * 16 + lrow];

  if (OM == 0) {
    float* outp = (float*)out1;
#pragma unroll
    for (int i = 0; i < 4; i++)
#pragma unroll
      for (int j = 0; j < 4; j++) {
        int n = nb + j * 16 + lrow;
#pragma unroll
        for (int r = 0; r < 4; r++) {
          int m = mbase + i * 16 + quad * 4 + r;
          outp[(size_t)m * N + n] = acc[i][j][r] + bn[j];
        }
      }
  } else {
    int seg = nb >> 10;                // 0=Q, 1=K, 2=V
    int hh = (nb & 1023) >> 6;         // head index
    if (seg < 2) {
      // RoPE: lane holds d = lrow(+16) and d+32 -> both pair halves local.
      ushort* dst = (seg == 0) ? (ushort*)out1 : (ushort*)out2;
      float scale = (seg == 0) ? QSCALE : 1.0f;
      float a0 = __builtin_amdgcn_exp2f((float)lrow * ROPE_C);
      float a1 = __builtin_amdgcn_exp2f((float)(lrow + 16) * ROPE_C);
#pragma unroll
      for (int i = 0; i < 4; i++) {
#pragma unroll
        for (int r = 0; r < 4; r++) {
          int m = mbase + i * 16 + quad * 4 + r;
          int t = m & (T - 1), bb = m >> 11;
          float s0, c0, s1, c1;
          __sincosf((float)t * a0, &s0, &c0);
          __sincosf((float)t * a1, &s1, &c1);
          float xr0 = acc[i][0][r] + bn[0];
          float xi0 = acc[i][2][r] + bn[2];
          float xr1 = acc[i][1][r] + bn[1];
          float xi1 = acc[i][3][r] + bn[3];
          ushort* p = dst + ((size_t)(bb * H + hh) * T + t) * D + lrow;
          p[0]  = f2bf((xr0 * c0 - xi0 * s0) * scale);
          p[32] = f2bf((xr0 * s0 + xi0 * c0) * scale);
          p[16] = f2bf((xr1 * c1 - xi1 * s1) * scale);
          p[48] = f2bf((xr1 * s1 + xi1 * c1) * scale);
        }
      }
    } else {
      // V: write transposed (B,H,D,T); 4 consecutive t per quad -> ushort4
      ushort* dst = (ushort*)out3;
#pragma unroll
      for (int i = 0; i < 4; i++) {
        int m0 = mbase + i * 16 + quad * 4;
        int t0 = m0 & (T - 1), bb = m0 >> 11;
        size_t base = (size_t)(bb * H + hh) * D * T + t0;
#pragma unroll
        for (int j = 0; j < 4; j++) {
          int d = j * 16 + lrow;
          ushort4 pk;
          pk.x = f2bf(acc[i][j][0] + bn[j]);
          pk.y = f2bf(acc[i][j][1] + bn[j]);
          pk.z = f2bf(acc[i][j][2] + bn[j]);
          pk.w = f2bf(acc[i][j][3] + bn[j]);
          *(ushort4*)(dst + base + (size_t)d * T) = pk;
        }
      }
    }
  }
}

// ---------------------------------------------------------------------------
// MFMA flash attention v4 (round-6 design, unchanged).
// ---------------------------------------------------------------------------
__device__ __forceinline__ void stage_kv(
    const ushort* kbh, const ushort* vbh, int s0,
    ushort* Kl, ushort* Vl, int tid) {
#pragma unroll
  for (int i = 0; i < 2; i++) {
    int c = tid + i * 256;
    int r = c >> 3, cc = c & 7;
    int g = (cc ^ (r & 7)) * 8;
    async_load16(kbh + (size_t)(s0 + r) * D + g, Kl + c * 8);
    async_load16(vbh + (size_t)r * T + s0 + g, Vl + c * 8);
  }
}

template <int MODE>
__device__ __forceinline__ void attn_step4(
    int s0, const ushort* KL, const ushort* VL, ushort* P,
    const bf16x8 (&qf)[2][2], int lrow, int quad, int sw0, int sw1,
    int qg0, int qg1, f32x4 (&o)[4][2], f32x4 (&ol)[2]) {
  bf16x8 kf0[4], kf1[4];
#pragma unroll
  for (int kt = 0; kt < 4; kt++) {
    int base = (kt * 16 + lrow) * 64;
    kf0[kt] = *(const bf16x8*)&KL[base + sw0];
    kf1[kt] = *(const bf16x8*)&KL[base + sw1];
  }
  bf16x8 vf0[4], vf1[4];
#pragma unroll
  for (int ds = 0; ds < 4; ds++) {
    int base = (ds * 16 + lrow) * 64;
    vf0[ds] = *(const bf16x8*)&VL[base + sw0];
    vf1[ds] = *(const bf16x8*)&VL[base + sw1];
  }
#pragma unroll
  for (int g = 0; g < 2; g++) {
    if (MODE == 2 && g == 0) continue;
    int qg = g ? qg1 : qg0;
    f32x4 st[4];
#pragma unroll
    for (int kt = 0; kt < 4; kt++) {
      f32x4 z = {0.f, 0.f, 0.f, 0.f};
      st[kt] = __builtin_amdgcn_mfma_f32_16x16x32_bf16(kf0[kt], qf[g][0], z, 0, 0, 0);
      st[kt] = __builtin_amdgcn_mfma_f32_16x16x32_bf16(kf1[kt], qf[g][1], st[kt], 0, 0, 0);
    }
    if ((MODE == 1 && g == 0) || (MODE == 2 && g == 1)) {
#pragma unroll
      for (int kt = 0; kt < 4; kt++)
#pragma unroll
        for (int r = 0; r < 4; r++)
          if (s0 + kt * 16 + quad * 4 + r > qg) st[kt][r] = -1e30f;
    }
#pragma unroll
    for (int kt = 0; kt < 4; kt++) {
      ushort4 pk;
      pk.x = f2bfr(__builtin_amdgcn_exp2f(st[kt][0]));
      pk.y = f2bfr(__builtin_amdgcn_exp2f(st[kt][1]));
      pk.z = f2bfr(__builtin_amdgcn_exp2f(st[kt][2]));
      pk.w = f2bfr(__builtin_amdgcn_exp2f(st[kt][3]));
      *(ushort4*)&P[((2 * kt + (quad >> 1)) * 32 + g * 16 + lrow) * 8 + (quad & 1) * 4] = pk;
    }
  }
  asm volatile("" ::: "memory");
  bf16x8 ones = ones_frag();
#pragma unroll
  for (int g = 0; g < 2; g++) {
    if (MODE == 2 && g == 0) continue;
    bf16x8 pf0 = *(const bf16x8*)&P[(quad * 32 + g * 16 + lrow) * 8];
    bf16x8 pf1 = *(const bf16x8*)&P[((quad + 4) * 32 + g * 16 + lrow) * 8];
    ol[g] = __builtin_amdgcn_mfma_f32_16x16x32_bf16(ones, pf0, ol[g], 0, 0, 0);
    ol[g] = __builtin_amdgcn_mfma_f32_16x16x32_bf16(ones, pf1, ol[g], 0, 0, 0);
#pragma unroll
    for (int ds = 0; ds < 4; ds++) {
      o[ds][g] = __builtin_amdgcn_mfma_f32_16x16x32_bf16(vf0[ds], pf0, o[ds][g], 0, 0, 0);
      o[ds][g] = __builtin_amdgcn_mfma_f32_16x16x32_bf16(vf1[ds], pf1, o[ds][g], 0, 0, 0);
    }
  }
}

__global__ __launch_bounds__(256, 3) void attn_mfma4(
    const ushort* __restrict__ qb_, const ushort* __restrict__ kb_,
    const ushort* __restrict__ vtb_, ushort* __restrict__ y) {
  __shared__ ushort Kl[2][64 * 64] __attribute__((aligned(16)));
  __shared__ ushort Vl[2][64 * 64] __attribute__((aligned(16)));
  __shared__ ushort Pl[4][2048] __attribute__((aligned(16)));
  int tid = threadIdx.x;
  int wave = tid >> 6, lane = tid & 63;
  int lrow = lane & 15, quad = lane >> 4;
  int qbi = 15 - (int)(blockIdx.x >> 6);
  int bh = blockIdx.x & 63;
  int b = bh >> 4, h = bh & 15;
  int Q0 = qbi * 128;
  ushort* P = Pl[wave];
  const ushort* kbh = kb_ + (size_t)bh * T * D;
  const ushort* vbh = vtb_ + (size_t)bh * D * T;

  int qg0 = Q0 + wave * 16 + lrow;
  int qg1 = qg0 + 64;
  bf16x8 qf[2][2];
  {
    const ushort* qp0 = qb_ + ((size_t)bh * T + qg0) * D + quad * 8;
    qf[0][0] = *(const bf16x8*)qp0;
    qf[0][1] = *(const bf16x8*)(qp0 + 32);
    const ushort* qp1 = qb_ + ((size_t)bh * T + qg1) * D + quad * 8;
    qf[1][0] = *(const bf16x8*)qp1;
    qf[1][1] = *(const bf16x8*)(qp1 + 32);
  }
  int r7 = lrow & 7;
  int sw0 = (quad ^ r7) * 8;
  int sw1 = ((quad + 4) ^ r7) * 8;

  f32x4 o[4][2];
#pragma unroll
  for (int ds = 0; ds < 4; ds++)
#pragma unroll
    for (int g = 0; g < 2; g++) o[ds][g] = (f32x4){0.f, 0.f, 0.f, 0.f};
  f32x4 ol[2] = {(f32x4){0.f, 0.f, 0.f, 0.f}, (f32x4){0.f, 0.f, 0.f, 0.f}};

  int trips = 2 * qbi + 2;
  stage_kv(kbh, vbh, 0, Kl[0], Vl[0], tid);
  int it = 0;
  for (; it < trips - 2; ++it) {
    __syncthreads();
    stage_kv(kbh, vbh, (it + 1) * 64, Kl[(it + 1) & 1], Vl[(it + 1) & 1], tid);
    attn_step4<0>(it * 64, Kl[it & 1], Vl[it & 1], P, qf, lrow, quad, sw0, sw1,
                  qg0, qg1, o, ol);
  }
  __syncthreads();
  stage_kv(kbh, vbh, (it + 1) * 64, Kl[(it + 1) & 1], Vl[(it + 1) & 1], tid);
  attn_step4<1>(it * 64, Kl[it & 1], Vl[it & 1], P, qf, lrow, quad, sw0, sw1,
                qg0, qg1, o, ol);
  ++it;
  __syncthreads();
  attn_step4<2>(it * 64, Kl[it & 1], Vl[it & 1], P, qf, lrow, quad, sw0, sw1,
                qg0, qg1, o, ol);

#pragma unroll
  for (int g = 0; g < 2; g++) {
    float inv = 1.f / ol[g][0];
    int qg = g ? qg1 : qg0;
#pragma unroll
    for (int ds = 0; ds < 4; ds++) {
      ushort4 pk;
      pk.x = f2bf(o[ds][g][0] * inv);
      pk.y = f2bf(o[ds][g][1] * inv);
      pk.z = f2bf(o[ds][g][2] * inv);
      pk.w = f2bf(o[ds][g][3] * inv);
      *(ushort4*)(y + ((size_t)b * T + qg) * C + h * D + ds * 16 + quad * 4) = pk;
    }
  }
}

// ---------------------------------------------------------------------------
extern "C" void kernel_launch(void* const* d_in, const int* in_sizes, int n_in,
                              void* d_out, int out_size, void* d_ws, size_t ws_size,
                              hipStream_t stream) {
  const float* x  = (const float*)d_in[0];
  const float* wq = (const float*)d_in[1];
  const float* bq = (const float*)d_in[2];
  const float* wk = (const float*)d_in[3];
  const float* bk = (const float*)d_in[4];
  const float* wv = (const float*)d_in[5];
  const float* bv = (const float*)d_in[6];
  const float* wp = (const float*)d_in[7];
  const float* bp = (const float*)d_in[8];
  float* out = (float*)d_out;

  ushort* xb    = (ushort*)d_ws;            // (B,T,C)   bf16
  ushort* qb    = xb + BTC;                 // (B,H,T,D) bf16 (exp2-scaled)
  ushort* kb    = qb + BTC;                 // (B,H,T,D) bf16
  ushort* vtb   = kb + BTC;                 // (B,H,D,T) bf16
  ushort* yb    = vtb + BTC;                // (B,T,C)   bf16
  ushort* wqkvb = yb + BTC;                 // (3C,C) bf16, wpb after
  ushort* wpb   = wqkvb + (size_t)3 * C * C;

  f32_to_bf16<<<(int)(BTC / 1024), 256, 0, stream>>>(x, xb);
  conv_weights<<<4 * (C * C) / 1024, 256, 0, stream>>>(wq, wk, wv, wp, wqkvb);

  // fused QKV GEMM: RoPE + layout transforms in epilogue
  dim3 qkv_grid(3 * C / GT, M / GT);        // (24, 64)
  gemm_mfma_bt<1><<<qkv_grid, 256, 0, stream>>>(
      xb, wqkvb, bq, bk, bv, qb, kb, vtb, 3 * C, C);

  attn_mfma4<<<(B * H * T / 128), 256, 0, stream>>>(qb, kb, vtb, yb);

  dim3 proj_grid(C / GT, M / GT);           // (8, 64)
  gemm_mfma_bt<0><<<proj_grid, 256, 0, stream>>>(
      yb, wpb, bp, bp, bp, out, nullptr, nullptr, C, C);
}